// Round 1
// baseline (3731.584 us; speedup 1.0000x reference)
//
#include <hip/hip_runtime.h>
#include <cstddef>

#define BATCH 32
#define NPTS  1024
#define K_NN  12
#define HID   64
#define BN_EPS 1e-5f

// ---------------------------------------------------------------------------
// kNN: j-split into 2 halves for parallelism (256 blocks -> 1 block/CU).
// Stable (d, j) lexicographic top-12 to match jax.lax.top_k tie-breaking.
// ---------------------------------------------------------------------------
template<int C>
__global__ __launch_bounds__(256) void knn_part_kernel(
    const float* __restrict__ x, float* __restrict__ cand_d, int* __restrict__ cand_j) {
  const int b = blockIdx.y;
  const int half = blockIdx.z;
  const int i = blockIdx.x * 256 + threadIdx.x;
  const float* xb = x + (size_t)b * NPTS * C;
  constexpr int CP = (C == 3) ? 4 : (C + 4);   // pad: +4 keeps 16B align, breaks stride-64 conflicts
  constexpr int TJ = 64;
  __shared__ float xjs[TJ * CP];
  __shared__ float d2s[TJ];

  float xi[C];
  float d2i = 0.f;
#pragma unroll
  for (int c = 0; c < C; ++c) { float v = xb[(size_t)i * C + c]; xi[c] = v; d2i = fmaf(v, v, d2i); }

  float bd[K_NN]; int bj[K_NN];
#pragma unroll
  for (int k = 0; k < K_NN; ++k) { bd[k] = 3.4e38f; bj[k] = 0x7fffffff; }

  const int j0 = half * (NPTS / 2);
  for (int tile = 0; tile < NPTS / 2; tile += TJ) {
    __syncthreads();
    for (int t = threadIdx.x; t < TJ * C; t += 256) {
      int r = t / C, c = t - r * C;
      xjs[r * CP + c] = xb[(size_t)(j0 + tile + r) * C + c];
    }
    __syncthreads();
    if (threadIdx.x < TJ) {
      float s = 0.f;
#pragma unroll 4
      for (int c = 0; c < C; ++c) { float v = xjs[threadIdx.x * CP + c]; s = fmaf(v, v, s); }
      d2s[threadIdx.x] = s;
    }
    __syncthreads();
    for (int jj = 0; jj < TJ; ++jj) {
      const float* xp = xjs + jj * CP;   // wave-uniform address -> LDS broadcast
      float dot;
      if constexpr (C >= 4) {
        float a0 = 0.f, a1 = 0.f, a2 = 0.f, a3 = 0.f;  // 4-way ILP (1 wave/SIMD)
#pragma unroll
        for (int c = 0; c < C; c += 4) {
          a0 = fmaf(xi[c + 0], xp[c + 0], a0);
          a1 = fmaf(xi[c + 1], xp[c + 1], a1);
          a2 = fmaf(xi[c + 2], xp[c + 2], a2);
          a3 = fmaf(xi[c + 3], xp[c + 3], a3);
        }
        dot = (a0 + a1) + (a2 + a3);
      } else {
        dot = 0.f;
#pragma unroll
        for (int c = 0; c < C; ++c) dot = fmaf(xi[c], xp[c], dot);
      }
      float d = fmaf(-2.f, dot, d2i + d2s[jj]);
      if (d < bd[K_NN - 1]) {
        float dk = d; int jk = j0 + tile + jj;
#pragma unroll
        for (int s = 0; s < K_NN; ++s) {
          // (d, j) lexicographic: keeps lower index on exact distance ties,
          // and carried duplicates displace correctly.
          bool sw = (dk < bd[s]) || (dk == bd[s] && jk < bj[s]);
          if (sw) { float td = bd[s]; int tj = bj[s]; bd[s] = dk; bj[s] = jk; dk = td; jk = tj; }
        }
      }
    }
  }
  float* cd = cand_d + ((size_t)(b * NPTS + i) * 2 + half) * K_NN;
  int*   cj = cand_j + ((size_t)(b * NPTS + i) * 2 + half) * K_NN;
#pragma unroll
  for (int k = 0; k < K_NN; ++k) { cd[k] = bd[k]; cj[k] = bj[k]; }
}

__global__ __launch_bounds__(256) void knn_merge_kernel(
    const float* __restrict__ cand_d, const int* __restrict__ cand_j, int* __restrict__ idx) {
  int row = blockIdx.x * 256 + threadIdx.x;    // 0..32767
  const float* cd = cand_d + (size_t)row * (2 * K_NN);
  const int*   cj = cand_j + (size_t)row * (2 * K_NN);
  float bd[K_NN]; int bj[K_NN];
#pragma unroll
  for (int k = 0; k < K_NN; ++k) { bd[k] = 3.4e38f; bj[k] = 0x7fffffff; }
#pragma unroll
  for (int t = 0; t < 2 * K_NN; ++t) {
    float dk = cd[t]; int jk = cj[t];
#pragma unroll
    for (int s = 0; s < K_NN; ++s) {
      bool sw = (dk < bd[s]) || (dk == bd[s] && jk < bj[s]);
      if (sw) { float td = bd[s]; int tj = bj[s]; bd[s] = dk; bj[s] = jk; dk = td; jk = tj; }
    }
  }
  int* op = idx + (size_t)row * K_NN;
#pragma unroll
  for (int k = 0; k < K_NN; ++k) op[k] = bj[k];
}

// ---------------------------------------------------------------------------
// EdgeConv main pass. STATS=true: accumulate BN sum/sumsq of h_pre = e@W1+b1.
// STATS=false: apply BN (A,B) + relu, sum over K, then (sum/12)@W2 + b2.
// Thread (nl, f): node nl of a 4-node group, output feature f. The xi-half of
// e@W1 is computed once per node; the (xj-xi)-half is register-blocked over
// 4 k's so the inner loop is 4 FMA per 1 W1 read (VALU-bound, not LDS-bound).
// ---------------------------------------------------------------------------
template<int C, bool STATS>
__global__ __launch_bounds__(256) void edgeconv_kernel(
    const float* __restrict__ xcur, const int* __restrict__ idx,
    const float* __restrict__ W1, const float* __restrict__ b1,
    const float* __restrict__ W2, const float* __restrict__ b2,
    float* __restrict__ stats, float* __restrict__ out) {
  constexpr int C2 = 2 * C;
  __shared__ float w1s[C2 * HID];
  __shared__ float w2s[STATS ? 1 : HID * HID];
  __shared__ float xis[4 * C];
  __shared__ float ejs[4 * K_NN * C];          // xj - xi, per edge
  __shared__ int   idxs[4 * K_NN];
  __shared__ float red[4 * HID];

  for (int t = threadIdx.x; t < C2 * HID; t += 256) w1s[t] = W1[t];
  if constexpr (!STATS)
    for (int t = threadIdx.x; t < HID * HID; t += 256) w2s[t] = W2[t];

  const int f  = threadIdx.x & 63;
  const int nl = threadIdx.x >> 6;
  const float b1f = b1[f];
  float A = 0.f, Bc = 0.f, b2f = 0.f;
  if constexpr (!STATS) { A = stats[2 * HID + f]; Bc = stats[3 * HID + f]; b2f = b2[f]; }
  float s1 = 0.f, s2 = 0.f;

  const int node0 = blockIdx.x * 64;           // global node (b*N + n)
  const int nbb = (node0 >> 10) << 10;         // b*N  (N = 1024)
  __syncthreads();

  for (int g4 = 0; g4 < 16; ++g4) {
    const int nbase = node0 + g4 * 4;
    __syncthreads();                            // protect prev-iter LDS reads
    if (threadIdx.x < 4 * K_NN)
      idxs[threadIdx.x] = idx[(size_t)nbase * K_NN + threadIdx.x];
    for (int t = threadIdx.x; t < 4 * C; t += 256) {
      int n2 = t / C, c = t - n2 * C;
      xis[t] = xcur[(size_t)(nbase + n2) * C + c];
    }
    __syncthreads();
    for (int t = threadIdx.x; t < 4 * K_NN * C; t += 256) {
      int e_l = t / C, c = t - e_l * C;         // e_l = nl2*12 + k
      int n2 = e_l / K_NN;
      int j = idxs[e_l];
      ejs[t] = xcur[(size_t)(nbb + j) * C + c] - xis[n2 * C + c];
    }
    __syncthreads();

    float hxi = b1f;                            // xi-half, shared over the 12 edges
#pragma unroll 4
    for (int c = 0; c < C; ++c) hxi = fmaf(xis[nl * C + c], w1s[c * HID + f], hxi);

    float hsum = 0.f;
#pragma unroll
    for (int kq = 0; kq < K_NN / 4; ++kq) {
      float h0 = hxi, h1 = hxi, h2 = hxi, h3 = hxi;
      const float* ep = ejs + (nl * K_NN + kq * 4) * C;
#pragma unroll 4
      for (int c = 0; c < C; ++c) {
        float w = w1s[(C + c) * HID + f];
        h0 = fmaf(ep[0 * C + c], w, h0);
        h1 = fmaf(ep[1 * C + c], w, h1);
        h2 = fmaf(ep[2 * C + c], w, h2);
        h3 = fmaf(ep[3 * C + c], w, h3);
      }
      if constexpr (STATS) {
        s1 += (h0 + h1) + (h2 + h3);
        s2 = fmaf(h0, h0, s2); s2 = fmaf(h1, h1, s2);
        s2 = fmaf(h2, h2, s2); s2 = fmaf(h3, h3, s2);
      } else {
        hsum += fmaxf(fmaf(A, h0, Bc), 0.f) + fmaxf(fmaf(A, h1, Bc), 0.f)
              + fmaxf(fmaf(A, h2, Bc), 0.f) + fmaxf(fmaf(A, h3, Bc), 0.f);
      }
    }

    if constexpr (!STATS) {
      red[nl * HID + f] = hsum;                 // mean-over-K commutes with W2
      __syncthreads();
      float acc = 0.f;
#pragma unroll 8
      for (int h = 0; h < HID; ++h) acc = fmaf(red[nl * HID + h], w2s[h * HID + f], acc);
      out[(size_t)(nbase + nl) * HID + f] = fmaf(acc, 1.f / (float)K_NN, b2f);
    }
  }

  if constexpr (STATS) {
    red[nl * HID + f] = s1;
    __syncthreads();
    if (threadIdx.x < HID)
      atomicAdd(&stats[f], ((red[f] + red[HID + f]) + (red[2 * HID + f] + red[3 * HID + f])));
    __syncthreads();
    red[nl * HID + f] = s2;
    __syncthreads();
    if (threadIdx.x < HID)
      atomicAdd(&stats[HID + f], ((red[f] + red[HID + f]) + (red[2 * HID + f] + red[3 * HID + f])));
  }
}

__global__ void bn_finalize_kernel(const float* __restrict__ g, const float* __restrict__ be,
                                   float* __restrict__ stats) {
  int f = threadIdx.x;
  const float inv_n = 1.f / (float)(BATCH * NPTS * K_NN);
  float m = stats[f] * inv_n;
  float v = stats[HID + f] * inv_n - m * m;
  float A = g[f] * rsqrtf(v + BN_EPS);
  stats[2 * HID + f] = A;
  stats[3 * HID + f] = be[f] - m * A;
}

// ---------------------------------------------------------------------------
__global__ __launch_bounds__(256) void pool_kernel(const float* __restrict__ h,
                                                   float* __restrict__ pooled) {
  const int b = blockIdx.x;
  const int f = threadIdx.x & 63;
  const int gsz = threadIdx.x >> 6;
  __shared__ float red[4][HID];
  float s = 0.f;
  for (int n = gsz; n < NPTS; n += 4) s += h[((size_t)b * NPTS + n) * HID + f];
  red[gsz][f] = s;
  __syncthreads();
  if (threadIdx.x < HID)
    pooled[b * HID + f] = ((red[0][f] + red[1][f]) + (red[2][f] + red[3][f])) * (1.f / (float)NPTS);
}

__global__ __launch_bounds__(256) void head_kernel(const float* __restrict__ pooled,
    const float* __restrict__ wf1, const float* __restrict__ bf1,
    const float* __restrict__ gf, const float* __restrict__ bef,
    const float* __restrict__ wf2, const float* __restrict__ bf2,
    float* __restrict__ out) {
  __shared__ float pl[BATCH * HID];
  __shared__ float t[BATCH * 32];
  __shared__ float Ab[32], Bb[32];
  for (int i = threadIdx.x; i < BATCH * HID; i += 256) pl[i] = pooled[i];
  __syncthreads();
  for (int i = threadIdx.x; i < BATCH * 32; i += 256) {
    int s = i >> 5, f1 = i & 31;
    float acc = bf1[f1];
    for (int h = 0; h < HID; ++h) acc = fmaf(pl[s * HID + h], wf1[h * 32 + f1], acc);
    t[i] = acc;
  }
  __syncthreads();
  if (threadIdx.x < 32) {
    int f1 = threadIdx.x;
    float m = 0.f;
    for (int s = 0; s < BATCH; ++s) m += t[s * 32 + f1];
    m *= (1.f / (float)BATCH);
    float v = 0.f;
    for (int s = 0; s < BATCH; ++s) { float d = t[s * 32 + f1] - m; v = fmaf(d, d, v); }
    v *= (1.f / (float)BATCH);
    float A = gf[f1] * rsqrtf(v + BN_EPS);
    Ab[f1] = A; Bb[f1] = bef[f1] - m * A;
  }
  __syncthreads();
  for (int i = threadIdx.x; i < BATCH * 32; i += 256) {
    int f1 = i & 31;
    t[i] = fmaxf(fmaf(Ab[f1], t[i], Bb[f1]), 0.f);
  }
  __syncthreads();
  if (threadIdx.x < BATCH * 2) {
    int s = threadIdx.x >> 1, o = threadIdx.x & 1;
    float acc = bf2[o];
    for (int f1 = 0; f1 < 32; ++f1) acc = fmaf(t[s * 32 + f1], wf2[f1 * 2 + o], acc);
    out[s * 2 + o] = acc;
  }
}

// ---------------------------------------------------------------------------
extern "C" void kernel_launch(void* const* d_in, const int* in_sizes, int n_in,
                              void* d_out, int out_size, void* d_ws, size_t ws_size,
                              hipStream_t stream) {
  const float* x   = (const float*)d_in[0];
  const float* w0a = (const float*)d_in[1];
  const float* b0a = (const float*)d_in[2];
  const float* g0  = (const float*)d_in[3];
  const float* be0 = (const float*)d_in[4];
  const float* w0b = (const float*)d_in[5];
  const float* b0b = (const float*)d_in[6];
  const float* wa  = (const float*)d_in[7];
  const float* ba  = (const float*)d_in[8];
  const float* ga  = (const float*)d_in[9];
  const float* bea = (const float*)d_in[10];
  const float* wb  = (const float*)d_in[11];
  const float* bb  = (const float*)d_in[12];
  const float* wf1 = (const float*)d_in[13];
  const float* bf1 = (const float*)d_in[14];
  const float* gf  = (const float*)d_in[15];
  const float* bef = (const float*)d_in[16];
  const float* wf2 = (const float*)d_in[17];
  const float* bf2 = (const float*)d_in[18];

  float* ws = (float*)d_ws;
  const size_t HN = (size_t)BATCH * NPTS * HID;         // 2,097,152
  const size_t ROWS = (size_t)BATCH * NPTS;             // 32768
  float* bufA   = ws;
  float* bufB   = bufA + HN;
  float* cand_d = bufB + HN;                            // ROWS*24 f
  int*   cand_j = (int*)(cand_d + ROWS * 2 * K_NN);     // ROWS*24 i
  int*   idxb   = cand_j + ROWS * 2 * K_NN;             // ROWS*12 i
  float* stats  = (float*)(idxb + ROWS * K_NN);         // 256 f
  float* pooled = stats + 4 * HID;                      // 2048 f
  // total ~24.7 MB of workspace

  auto layer = [&](const float* cur, float* nxt, const float* W1, const float* b1p,
                   const float* g, const float* be, const float* W2, const float* b2p,
                   bool first) {
    if (first) knn_part_kernel<3  ><<<dim3(4, BATCH, 2), 256, 0, stream>>>(cur, cand_d, cand_j);
    else       knn_part_kernel<HID><<<dim3(4, BATCH, 2), 256, 0, stream>>>(cur, cand_d, cand_j);
    knn_merge_kernel<<<128, 256, 0, stream>>>(cand_d, cand_j, idxb);
    hipMemsetAsync(stats, 0, 2 * HID * sizeof(float), stream);
    if (first) edgeconv_kernel<3,   true ><<<512, 256, 0, stream>>>(cur, idxb, W1, b1p, nullptr, nullptr, stats, nullptr);
    else       edgeconv_kernel<HID, true ><<<512, 256, 0, stream>>>(cur, idxb, W1, b1p, nullptr, nullptr, stats, nullptr);
    bn_finalize_kernel<<<1, HID, 0, stream>>>(g, be, stats);
    if (first) edgeconv_kernel<3,   false><<<512, 256, 0, stream>>>(cur, idxb, W1, b1p, W2, b2p, stats, nxt);
    else       edgeconv_kernel<HID, false><<<512, 256, 0, stream>>>(cur, idxb, W1, b1p, W2, b2p, stats, nxt);
  };

  layer(x,    bufA, w0a,               b0a,      g0,       be0,       w0b,              b0b,      true);
  layer(bufA, bufB, wa + 0 * 128 * 64, ba + 0,   ga + 0,   bea + 0,   wb + 0 * 64 * 64, bb + 0,   false);
  layer(bufB, bufA, wa + 1 * 128 * 64, ba + 64,  ga + 64,  bea + 64,  wb + 1 * 64 * 64, bb + 64,  false);
  layer(bufA, bufB, wa + 2 * 128 * 64, ba + 128, ga + 128, bea + 128, wb + 2 * 64 * 64, bb + 128, false);

  pool_kernel<<<BATCH, 256, 0, stream>>>(bufB, pooled);
  head_kernel<<<1, 256, 0, stream>>>(pooled, wf1, bf1, gf, bef, wf2, bf2, (float*)d_out);
}

// Round 2
// 2928.747 us; speedup vs baseline: 1.2741x; 1.2741x over previous
//
#include <hip/hip_runtime.h>
#include <cstddef>

#define BATCH 32
#define NPTS  1024
#define K_NN  12
#define HID   64
#define BN_EPS 1e-5f

// ---------------------------------------------------------------------------
// d2[j] = ||x_j||^2 precompute (wave-uniform consumer in knn reads via s_load).
// ---------------------------------------------------------------------------
template<int C>
__global__ __launch_bounds__(256) void d2_kernel(const float* __restrict__ x,
                                                 float* __restrict__ d2) {
  int gid = blockIdx.x * 256 + threadIdx.x;          // < B*N
  const float* xp = x + (size_t)gid * C;
  float s;
  if constexpr (C % 4 == 0) {
    const float4* x4 = (const float4*)xp;
    float a0 = 0.f, a1 = 0.f, a2 = 0.f, a3 = 0.f;
#pragma unroll
    for (int q = 0; q < C / 4; ++q) {
      float4 v = x4[q];
      a0 = fmaf(v.x, v.x, a0); a1 = fmaf(v.y, v.y, a1);
      a2 = fmaf(v.z, v.z, a2); a3 = fmaf(v.w, v.w, a3);
    }
    s = (a0 + a1) + (a2 + a3);
  } else {
    s = 0.f;
#pragma unroll
    for (int c = 0; c < C; ++c) { float v = xp[c]; s = fmaf(v, v, s); }
  }
  d2[gid] = s;
}

// ---------------------------------------------------------------------------
// kNN v3: lane = point i (xi fully register-resident), wave-uniform j streamed
// through SGPRs (compiler-scalarized s_load: address depends only on block/loop
// vars). Per-row constant d2_i is dropped (doesn't affect per-row top-k order):
// dval = d2_j - 2*dot(xi,xj). 8 waves per block each scan a 128-j slice of the
// same 64 i's; slices merged via LDS by wave 0. Strict `<` insertion scanning j
// ascending == jax.lax.top_k stable tie-break (lower index wins on ties).
// ---------------------------------------------------------------------------
template<int C>
__global__ __launch_bounds__(512, 4) void knn_kernel(
    const float* __restrict__ x, const float* __restrict__ d2,
    int* __restrict__ idx) {
  const int b    = blockIdx.y;
  const int lane = threadIdx.x & 63;
  const int wv   = threadIdx.x >> 6;                 // 0..7
  const int i    = blockIdx.x * 64 + lane;
  const float* xb  = x  + (size_t)b * NPTS * C;
  const float* d2b = d2 + (size_t)b * NPTS;

  constexpr int NE = 8 * K_NN;                       // 96 merge entries/row
  __shared__ float lds_d[64][NE + 1];                // +1: stride 97 (96%32==0!)
  __shared__ int   lds_j[64][NE + 1];

  float xi[C];
  if constexpr (C % 4 == 0) {
    const float4* xr = (const float4*)(xb + (size_t)i * C);
#pragma unroll
    for (int q = 0; q < C / 4; ++q) {
      float4 v = xr[q];
      xi[4 * q + 0] = v.x; xi[4 * q + 1] = v.y;
      xi[4 * q + 2] = v.z; xi[4 * q + 3] = v.w;
    }
  } else {
#pragma unroll
    for (int c = 0; c < C; ++c) xi[c] = xb[(size_t)i * C + c];
  }

  float bd[K_NN]; int bj[K_NN];
#pragma unroll
  for (int k = 0; k < K_NN; ++k) { bd[k] = 3.4e38f; bj[k] = 0x7fffffff; }

  const int j0 = wv * (NPTS / 8);
  for (int jj = 0; jj < NPTS / 8; ++jj) {
    const int j = j0 + jj;
    const float* xj = xb + (size_t)j * C;            // wave-uniform -> s_load
    const float d2j = d2b[j];                        // wave-uniform -> s_load
    float dot;
    if constexpr (C % 4 == 0) {
      float a0 = 0.f, a1 = 0.f, a2 = 0.f, a3 = 0.f;  // 4-way ILP on the chain
#pragma unroll
      for (int c = 0; c < C; c += 4) {
        a0 = fmaf(xi[c + 0], xj[c + 0], a0);
        a1 = fmaf(xi[c + 1], xj[c + 1], a1);
        a2 = fmaf(xi[c + 2], xj[c + 2], a2);
        a3 = fmaf(xi[c + 3], xj[c + 3], a3);
      }
      dot = (a0 + a1) + (a2 + a3);
    } else {
      dot = 0.f;
#pragma unroll
      for (int c = 0; c < C; ++c) dot = fmaf(xi[c], xj[c], dot);
    }
    const float dval = fmaf(-2.f, dot, d2j);
    if (dval < bd[K_NN - 1]) {                       // strict <: ties rejected,
      float dk = dval; int jk = j;                   // lower j kept (stable)
#pragma unroll
      for (int s = 0; s < K_NN; ++s) {
        bool sw = dk < bd[s];
        if (sw) { float td = bd[s]; int tj = bj[s]; bd[s] = dk; bj[s] = jk; dk = td; jk = tj; }
      }
    }
  }

#pragma unroll
  for (int k = 0; k < K_NN; ++k) {
    lds_d[lane][wv * K_NN + k] = bd[k];
    lds_j[lane][wv * K_NN + k] = bj[k];
  }
  __syncthreads();

  if (wv == 0) {                                     // merge 8 sorted slices
    float md[K_NN]; int mj[K_NN];
#pragma unroll
    for (int k = 0; k < K_NN; ++k) { md[k] = 3.4e38f; mj[k] = 0x7fffffff; }
    for (int e = 0; e < NE; ++e) {                   // ascending slice order ->
      float dk = lds_d[lane][e]; int jk = lds_j[lane][e];  // stability kept
      if (dk < md[K_NN - 1]) {
#pragma unroll
        for (int s = 0; s < K_NN; ++s) {
          bool sw = dk < md[s];
          if (sw) { float td = md[s]; int tj = mj[s]; md[s] = dk; mj[s] = jk; dk = td; jk = tj; }
        }
      }
    }
    int* op = idx + ((size_t)b * NPTS + blockIdx.x * 64 + lane) * K_NN;
#pragma unroll
    for (int k = 0; k < K_NN; ++k) op[k] = mj[k];
  }
}

// ---------------------------------------------------------------------------
// EdgeConv main pass. STATS=true: accumulate BN sum/sumsq of h_pre = e@W1+b1.
// STATS=false: apply BN (A,B) + relu, sum over K, then (sum/12)@W2 + b2.
// ---------------------------------------------------------------------------
template<int C, bool STATS>
__global__ __launch_bounds__(256) void edgeconv_kernel(
    const float* __restrict__ xcur, const int* __restrict__ idx,
    const float* __restrict__ W1, const float* __restrict__ b1,
    const float* __restrict__ W2, const float* __restrict__ b2,
    float* __restrict__ stats, float* __restrict__ out) {
  constexpr int C2 = 2 * C;
  __shared__ float w1s[C2 * HID];
  __shared__ float w2s[STATS ? 1 : HID * HID];
  __shared__ float xis[4 * C];
  __shared__ float ejs[4 * K_NN * C];          // xj - xi, per edge
  __shared__ int   idxs[4 * K_NN];
  __shared__ float red[4 * HID];

  for (int t = threadIdx.x; t < C2 * HID; t += 256) w1s[t] = W1[t];
  if constexpr (!STATS)
    for (int t = threadIdx.x; t < HID * HID; t += 256) w2s[t] = W2[t];

  const int f  = threadIdx.x & 63;
  const int nl = threadIdx.x >> 6;
  const float b1f = b1[f];
  float A = 0.f, Bc = 0.f, b2f = 0.f;
  if constexpr (!STATS) { A = stats[2 * HID + f]; Bc = stats[3 * HID + f]; b2f = b2[f]; }
  float s1 = 0.f, s2 = 0.f;

  const int node0 = blockIdx.x * 64;           // global node (b*N + n)
  const int nbb = (node0 >> 10) << 10;         // b*N  (N = 1024)
  __syncthreads();

  for (int g4 = 0; g4 < 16; ++g4) {
    const int nbase = node0 + g4 * 4;
    __syncthreads();                            // protect prev-iter LDS reads
    if (threadIdx.x < 4 * K_NN)
      idxs[threadIdx.x] = idx[(size_t)nbase * K_NN + threadIdx.x];
    for (int t = threadIdx.x; t < 4 * C; t += 256) {
      int n2 = t / C, c = t - n2 * C;
      xis[t] = xcur[(size_t)(nbase + n2) * C + c];
    }
    __syncthreads();
    for (int t = threadIdx.x; t < 4 * K_NN * C; t += 256) {
      int e_l = t / C, c = t - e_l * C;         // e_l = nl2*12 + k
      int n2 = e_l / K_NN;
      int j = idxs[e_l];
      ejs[t] = xcur[(size_t)(nbb + j) * C + c] - xis[n2 * C + c];
    }
    __syncthreads();

    float hxi = b1f;                            // xi-half, shared over the 12 edges
#pragma unroll 4
    for (int c = 0; c < C; ++c) hxi = fmaf(xis[nl * C + c], w1s[c * HID + f], hxi);

    float hsum = 0.f;
#pragma unroll
    for (int kq = 0; kq < K_NN / 4; ++kq) {
      float h0 = hxi, h1 = hxi, h2 = hxi, h3 = hxi;
      const float* ep = ejs + (nl * K_NN + kq * 4) * C;
#pragma unroll 4
      for (int c = 0; c < C; ++c) {
        float w = w1s[(C + c) * HID + f];
        h0 = fmaf(ep[0 * C + c], w, h0);
        h1 = fmaf(ep[1 * C + c], w, h1);
        h2 = fmaf(ep[2 * C + c], w, h2);
        h3 = fmaf(ep[3 * C + c], w, h3);
      }
      if constexpr (STATS) {
        s1 += (h0 + h1) + (h2 + h3);
        s2 = fmaf(h0, h0, s2); s2 = fmaf(h1, h1, s2);
        s2 = fmaf(h2, h2, s2); s2 = fmaf(h3, h3, s2);
      } else {
        hsum += fmaxf(fmaf(A, h0, Bc), 0.f) + fmaxf(fmaf(A, h1, Bc), 0.f)
              + fmaxf(fmaf(A, h2, Bc), 0.f) + fmaxf(fmaf(A, h3, Bc), 0.f);
      }
    }

    if constexpr (!STATS) {
      red[nl * HID + f] = hsum;                 // mean-over-K commutes with W2
      __syncthreads();
      float acc = 0.f;
#pragma unroll 8
      for (int h = 0; h < HID; ++h) acc = fmaf(red[nl * HID + h], w2s[h * HID + f], acc);
      out[(size_t)(nbase + nl) * HID + f] = fmaf(acc, 1.f / (float)K_NN, b2f);
    }
  }

  if constexpr (STATS) {
    red[nl * HID + f] = s1;
    __syncthreads();
    if (threadIdx.x < HID)
      atomicAdd(&stats[f], ((red[f] + red[HID + f]) + (red[2 * HID + f] + red[3 * HID + f])));
    __syncthreads();
    red[nl * HID + f] = s2;
    __syncthreads();
    if (threadIdx.x < HID)
      atomicAdd(&stats[HID + f], ((red[f] + red[HID + f]) + (red[2 * HID + f] + red[3 * HID + f])));
  }
}

__global__ void bn_finalize_kernel(const float* __restrict__ g, const float* __restrict__ be,
                                   float* __restrict__ stats) {
  int f = threadIdx.x;
  const float inv_n = 1.f / (float)(BATCH * NPTS * K_NN);
  float m = stats[f] * inv_n;
  float v = stats[HID + f] * inv_n - m * m;
  float A = g[f] * rsqrtf(v + BN_EPS);
  stats[2 * HID + f] = A;
  stats[3 * HID + f] = be[f] - m * A;
}

// ---------------------------------------------------------------------------
__global__ __launch_bounds__(256) void pool_kernel(const float* __restrict__ h,
                                                   float* __restrict__ pooled) {
  const int b = blockIdx.x;
  const int f = threadIdx.x & 63;
  const int gsz = threadIdx.x >> 6;
  __shared__ float red[4][HID];
  float s = 0.f;
  for (int n = gsz; n < NPTS; n += 4) s += h[((size_t)b * NPTS + n) * HID + f];
  red[gsz][f] = s;
  __syncthreads();
  if (threadIdx.x < HID)
    pooled[b * HID + f] = ((red[0][f] + red[1][f]) + (red[2][f] + red[3][f])) * (1.f / (float)NPTS);
}

__global__ __launch_bounds__(256) void head_kernel(const float* __restrict__ pooled,
    const float* __restrict__ wf1, const float* __restrict__ bf1,
    const float* __restrict__ gf, const float* __restrict__ bef,
    const float* __restrict__ wf2, const float* __restrict__ bf2,
    float* __restrict__ out) {
  __shared__ float pl[BATCH * HID];
  __shared__ float t[BATCH * 32];
  __shared__ float Ab[32], Bb[32];
  for (int i = threadIdx.x; i < BATCH * HID; i += 256) pl[i] = pooled[i];
  __syncthreads();
  for (int i = threadIdx.x; i < BATCH * 32; i += 256) {
    int s = i >> 5, f1 = i & 31;
    float acc = bf1[f1];
    for (int h = 0; h < HID; ++h) acc = fmaf(pl[s * HID + h], wf1[h * 32 + f1], acc);
    t[i] = acc;
  }
  __syncthreads();
  if (threadIdx.x < 32) {
    int f1 = threadIdx.x;
    float m = 0.f;
    for (int s = 0; s < BATCH; ++s) m += t[s * 32 + f1];
    m *= (1.f / (float)BATCH);
    float v = 0.f;
    for (int s = 0; s < BATCH; ++s) { float d = t[s * 32 + f1] - m; v = fmaf(d, d, v); }
    v *= (1.f / (float)BATCH);
    float A = gf[f1] * rsqrtf(v + BN_EPS);
    Ab[f1] = A; Bb[f1] = bef[f1] - m * A;
  }
  __syncthreads();
  for (int i = threadIdx.x; i < BATCH * 32; i += 256) {
    int f1 = i & 31;
    t[i] = fmaxf(fmaf(Ab[f1], t[i], Bb[f1]), 0.f);
  }
  __syncthreads();
  if (threadIdx.x < BATCH * 2) {
    int s = threadIdx.x >> 1, o = threadIdx.x & 1;
    float acc = bf2[o];
    for (int f1 = 0; f1 < 32; ++f1) acc = fmaf(t[s * 32 + f1], wf2[f1 * 2 + o], acc);
    out[s * 2 + o] = acc;
  }
}

// ---------------------------------------------------------------------------
extern "C" void kernel_launch(void* const* d_in, const int* in_sizes, int n_in,
                              void* d_out, int out_size, void* d_ws, size_t ws_size,
                              hipStream_t stream) {
  const float* x   = (const float*)d_in[0];
  const float* w0a = (const float*)d_in[1];
  const float* b0a = (const float*)d_in[2];
  const float* g0  = (const float*)d_in[3];
  const float* be0 = (const float*)d_in[4];
  const float* w0b = (const float*)d_in[5];
  const float* b0b = (const float*)d_in[6];
  const float* wa  = (const float*)d_in[7];
  const float* ba  = (const float*)d_in[8];
  const float* ga  = (const float*)d_in[9];
  const float* bea = (const float*)d_in[10];
  const float* wb  = (const float*)d_in[11];
  const float* bb  = (const float*)d_in[12];
  const float* wf1 = (const float*)d_in[13];
  const float* bf1 = (const float*)d_in[14];
  const float* gf  = (const float*)d_in[15];
  const float* bef = (const float*)d_in[16];
  const float* wf2 = (const float*)d_in[17];
  const float* bf2 = (const float*)d_in[18];

  float* ws = (float*)d_ws;
  const size_t HN = (size_t)BATCH * NPTS * HID;         // 2,097,152
  const size_t ROWS = (size_t)BATCH * NPTS;             // 32768
  float* bufA   = ws;
  float* bufB   = bufA + HN;
  int*   idxb   = (int*)(bufB + HN);                    // ROWS*12 i
  float* d2buf  = (float*)(idxb + ROWS * K_NN);         // ROWS f
  float* stats  = d2buf + ROWS;                         // 256 f
  float* pooled = stats + 4 * HID;                      // 2048 f
  // total ~18.2 MB of workspace

  auto layer = [&](const float* cur, float* nxt, const float* W1, const float* b1p,
                   const float* g, const float* be, const float* W2, const float* b2p,
                   bool first) {
    if (first) {
      d2_kernel<3 ><<<(int)(ROWS / 256), 256, 0, stream>>>(cur, d2buf);
      knn_kernel<3 ><<<dim3(16, BATCH), 512, 0, stream>>>(cur, d2buf, idxb);
    } else {
      d2_kernel<HID><<<(int)(ROWS / 256), 256, 0, stream>>>(cur, d2buf);
      knn_kernel<HID><<<dim3(16, BATCH), 512, 0, stream>>>(cur, d2buf, idxb);
    }
    hipMemsetAsync(stats, 0, 2 * HID * sizeof(float), stream);
    if (first) edgeconv_kernel<3,   true ><<<512, 256, 0, stream>>>(cur, idxb, W1, b1p, nullptr, nullptr, stats, nullptr);
    else       edgeconv_kernel<HID, true ><<<512, 256, 0, stream>>>(cur, idxb, W1, b1p, nullptr, nullptr, stats, nullptr);
    bn_finalize_kernel<<<1, HID, 0, stream>>>(g, be, stats);
    if (first) edgeconv_kernel<3,   false><<<512, 256, 0, stream>>>(cur, idxb, W1, b1p, W2, b2p, stats, nxt);
    else       edgeconv_kernel<HID, false><<<512, 256, 0, stream>>>(cur, idxb, W1, b1p, W2, b2p, stats, nxt);
  };

  layer(x,    bufA, w0a,               b0a,      g0,       be0,       w0b,              b0b,      true);
  layer(bufA, bufB, wa + 0 * 128 * 64, ba + 0,   ga + 0,   bea + 0,   wb + 0 * 64 * 64, bb + 0,   false);
  layer(bufB, bufA, wa + 1 * 128 * 64, ba + 64,  ga + 64,  bea + 64,  wb + 1 * 64 * 64, bb + 64,  false);
  layer(bufA, bufB, wa + 2 * 128 * 64, ba + 128, ga + 128, bea + 128, wb + 2 * 64 * 64, bb + 128, false);

  pool_kernel<<<BATCH, 256, 0, stream>>>(bufB, pooled);
  head_kernel<<<1, 256, 0, stream>>>(pooled, wf1, bf1, gf, bef, wf2, bf2, (float*)d_out);
}

// Round 3
// 2028.285 us; speedup vs baseline: 1.8398x; 1.4440x over previous
//
#include <hip/hip_runtime.h>
#include <cstddef>

#define BATCH 32
#define NPTS  1024
#define K_NN  12
#define HID   64
#define BN_EPS 1e-5f

// ---------------------------------------------------------------------------
// d2[j] = ||x_j||^2 precompute.
// ---------------------------------------------------------------------------
template<int C>
__global__ __launch_bounds__(256) void d2_kernel(const float* __restrict__ x,
                                                 float* __restrict__ d2) {
  int gid = blockIdx.x * 256 + threadIdx.x;          // < B*N
  const float* xp = x + (size_t)gid * C;
  float s;
  if constexpr (C % 4 == 0) {
    const float4* x4 = (const float4*)xp;
    float a0 = 0.f, a1 = 0.f, a2 = 0.f, a3 = 0.f;
#pragma unroll
    for (int q = 0; q < C / 4; ++q) {
      float4 v = x4[q];
      a0 = fmaf(v.x, v.x, a0); a1 = fmaf(v.y, v.y, a1);
      a2 = fmaf(v.z, v.z, a2); a3 = fmaf(v.w, v.w, a3);
    }
    s = (a0 + a1) + (a2 + a3);
  } else {
    s = 0.f;
#pragma unroll
    for (int c = 0; c < C; ++c) { float v = xp[c]; s = fmaf(v, v, s); }
  }
  d2[gid] = s;
}

// ---------------------------------------------------------------------------
// kNN v4: lane = point i, xi PINNED in VGPRs (inline-asm defeats the
// allocator's load-rematerialization that caused R2's VGPR=64 + 42MB fetch).
// j is made provably wave-uniform via readfirstlane so xj/d2j compile to
// s_load on the scalar pipe (consumed as the one SGPR operand of v_fma).
// 8 waves/block scan 128-j slices; merged via LDS by wave 0.
// amdgpu_waves_per_eu(2,4): aim 4 waves/EU (<=128 VGPR), not 8 (<=64).
// ---------------------------------------------------------------------------
template<int C>
__global__ __attribute__((amdgpu_flat_work_group_size(512, 512),
                          amdgpu_waves_per_eu(2, 4)))
void knn_kernel(const float* __restrict__ x, const float* __restrict__ d2,
                int* __restrict__ idx) {
  const int b    = blockIdx.y;
  const int lane = threadIdx.x & 63;
  const int wv_u = __builtin_amdgcn_readfirstlane(threadIdx.x >> 6);  // 0..7, SGPR
  const int i    = blockIdx.x * 64 + lane;
  const float* xb  = x  + (size_t)b * NPTS * C;
  const float* d2b = d2 + (size_t)b * NPTS;

  constexpr int NE = 8 * K_NN;                       // 96 merge entries/row
  __shared__ float lds_d[64][NE + 1];                // stride 97: odd, no conflicts
  __shared__ int   lds_j[64][NE + 1];

  float xi[C];
  if constexpr (C % 4 == 0) {
    const float4* xr = (const float4*)(xb + (size_t)i * C);
#pragma unroll
    for (int q = 0; q < C / 4; ++q) {
      float4 v = xr[q];
      xi[4 * q + 0] = v.x; xi[4 * q + 1] = v.y;
      xi[4 * q + 2] = v.z; xi[4 * q + 3] = v.w;
    }
  } else {
#pragma unroll
    for (int c = 0; c < C; ++c) xi[c] = xb[(size_t)i * C + c];
  }
  if constexpr (C >= 16) {
#pragma unroll
    for (int c = 0; c < C; ++c) asm volatile("" : "+v"(xi[c]));  // pin: no remat
  }

  float bd[K_NN]; int bj[K_NN];
#pragma unroll
  for (int k = 0; k < K_NN; ++k) { bd[k] = 3.4e38f; bj[k] = 0x7fffffff; }

  const int j0 = wv_u * (NPTS / 8);                  // uniform
#pragma unroll 1
  for (int jj = 0; jj < NPTS / 8; ++jj) {
    const int j = j0 + jj;                           // uniform
    const float* xj = xb + (size_t)j * C;            // uniform -> s_load
    const float d2j = d2b[j];                        // uniform -> s_load
    float dot;
    if constexpr (C % 4 == 0) {
      float a0 = 0.f, a1 = 0.f, a2 = 0.f, a3 = 0.f;
#pragma unroll
      for (int c = 0; c < C; c += 4) {
        a0 = fmaf(xi[c + 0], xj[c + 0], a0);
        a1 = fmaf(xi[c + 1], xj[c + 1], a1);
        a2 = fmaf(xi[c + 2], xj[c + 2], a2);
        a3 = fmaf(xi[c + 3], xj[c + 3], a3);
      }
      dot = (a0 + a1) + (a2 + a3);
    } else {
      dot = 0.f;
#pragma unroll
      for (int c = 0; c < C; ++c) dot = fmaf(xi[c], xj[c], dot);
    }
    // d2_i (row-constant) dropped: doesn't change per-row top-k order.
    const float dval = fmaf(-2.f, dot, d2j);
    if (dval < bd[K_NN - 1]) {                       // strict <: scanning j
      float dk = dval; int jk = j;                   // ascending keeps lower j
#pragma unroll
      for (int s = 0; s < K_NN; ++s) {               // branchless sorted insert
        bool sw = dk < bd[s];
        float nd = fminf(dk, bd[s]);
        float xd = fmaxf(dk, bd[s]);
        int nj = sw ? jk : bj[s];
        int xjj = sw ? bj[s] : jk;
        bd[s] = nd; bj[s] = nj; dk = xd; jk = xjj;
      }
    }
  }

#pragma unroll
  for (int k = 0; k < K_NN; ++k) {
    lds_d[lane][wv_u * K_NN + k] = bd[k];
    lds_j[lane][wv_u * K_NN + k] = bj[k];
  }
  __syncthreads();

  if (wv_u == 0) {                                   // merge 8 sorted slices
    float md[K_NN]; int mj[K_NN];
#pragma unroll
    for (int k = 0; k < K_NN; ++k) { md[k] = 3.4e38f; mj[k] = 0x7fffffff; }
    for (int e = 0; e < NE; ++e) {                   // ascending slice order ->
      float dk = lds_d[lane][e]; int jk = lds_j[lane][e];  // stability kept
      if (dk < md[K_NN - 1]) {
#pragma unroll
        for (int s = 0; s < K_NN; ++s) {
          bool sw = dk < md[s];
          float nd = fminf(dk, md[s]);
          float xd = fmaxf(dk, md[s]);
          int nj = sw ? jk : mj[s];
          int xjj = sw ? mj[s] : jk;
          md[s] = nd; mj[s] = nj; dk = xd; jk = xjj;
        }
      }
    }
    int* op = idx + ((size_t)b * NPTS + blockIdx.x * 64 + lane) * K_NN;
#pragma unroll
    for (int k = 0; k < K_NN; ++k) op[k] = mj[k];
  }
}

// ---------------------------------------------------------------------------
// EdgeConv main pass. STATS=true: accumulate BN sum/sumsq of h_pre = e@W1+b1.
// STATS=false: apply BN (A,B) + relu, sum over K, then (sum/12)@W2 + b2.
// ---------------------------------------------------------------------------
template<int C, bool STATS>
__global__ __launch_bounds__(256) void edgeconv_kernel(
    const float* __restrict__ xcur, const int* __restrict__ idx,
    const float* __restrict__ W1, const float* __restrict__ b1,
    const float* __restrict__ W2, const float* __restrict__ b2,
    float* __restrict__ stats, float* __restrict__ out) {
  constexpr int C2 = 2 * C;
  __shared__ float w1s[C2 * HID];
  __shared__ float w2s[STATS ? 1 : HID * HID];
  __shared__ float xis[4 * C];
  __shared__ float ejs[4 * K_NN * C];          // xj - xi, per edge
  __shared__ int   idxs[4 * K_NN];
  __shared__ float red[4 * HID];

  for (int t = threadIdx.x; t < C2 * HID; t += 256) w1s[t] = W1[t];
  if constexpr (!STATS)
    for (int t = threadIdx.x; t < HID * HID; t += 256) w2s[t] = W2[t];

  const int f  = threadIdx.x & 63;
  const int nl = threadIdx.x >> 6;
  const float b1f = b1[f];
  float A = 0.f, Bc = 0.f, b2f = 0.f;
  if constexpr (!STATS) { A = stats[2 * HID + f]; Bc = stats[3 * HID + f]; b2f = b2[f]; }
  float s1 = 0.f, s2 = 0.f;

  const int node0 = blockIdx.x * 64;           // global node (b*N + n)
  const int nbb = (node0 >> 10) << 10;         // b*N  (N = 1024)
  __syncthreads();

  for (int g4 = 0; g4 < 16; ++g4) {
    const int nbase = node0 + g4 * 4;
    __syncthreads();                            // protect prev-iter LDS reads
    if (threadIdx.x < 4 * K_NN)
      idxs[threadIdx.x] = idx[(size_t)nbase * K_NN + threadIdx.x];
    for (int t = threadIdx.x; t < 4 * C; t += 256) {
      int n2 = t / C, c = t - n2 * C;
      xis[t] = xcur[(size_t)(nbase + n2) * C + c];
    }
    __syncthreads();
    for (int t = threadIdx.x; t < 4 * K_NN * C; t += 256) {
      int e_l = t / C, c = t - e_l * C;         // e_l = nl2*12 + k
      int n2 = e_l / K_NN;
      int j = idxs[e_l];
      ejs[t] = xcur[(size_t)(nbb + j) * C + c] - xis[n2 * C + c];
    }
    __syncthreads();

    float hxi = b1f;                            // xi-half, shared over the 12 edges
#pragma unroll 4
    for (int c = 0; c < C; ++c) hxi = fmaf(xis[nl * C + c], w1s[c * HID + f], hxi);

    float hsum = 0.f;
#pragma unroll
    for (int kq = 0; kq < K_NN / 4; ++kq) {
      float h0 = hxi, h1 = hxi, h2 = hxi, h3 = hxi;
      const float* ep = ejs + (nl * K_NN + kq * 4) * C;
#pragma unroll 4
      for (int c = 0; c < C; ++c) {
        float w = w1s[(C + c) * HID + f];
        h0 = fmaf(ep[0 * C + c], w, h0);
        h1 = fmaf(ep[1 * C + c], w, h1);
        h2 = fmaf(ep[2 * C + c], w, h2);
        h3 = fmaf(ep[3 * C + c], w, h3);
      }
      if constexpr (STATS) {
        s1 += (h0 + h1) + (h2 + h3);
        s2 = fmaf(h0, h0, s2); s2 = fmaf(h1, h1, s2);
        s2 = fmaf(h2, h2, s2); s2 = fmaf(h3, h3, s2);
      } else {
        hsum += fmaxf(fmaf(A, h0, Bc), 0.f) + fmaxf(fmaf(A, h1, Bc), 0.f)
              + fmaxf(fmaf(A, h2, Bc), 0.f) + fmaxf(fmaf(A, h3, Bc), 0.f);
      }
    }

    if constexpr (!STATS) {
      red[nl * HID + f] = hsum;                 // mean-over-K commutes with W2
      __syncthreads();
      float acc = 0.f;
#pragma unroll 8
      for (int h = 0; h < HID; ++h) acc = fmaf(red[nl * HID + h], w2s[h * HID + f], acc);
      out[(size_t)(nbase + nl) * HID + f] = fmaf(acc, 1.f / (float)K_NN, b2f);
    }
  }

  if constexpr (STATS) {
    red[nl * HID + f] = s1;
    __syncthreads();
    if (threadIdx.x < HID)
      atomicAdd(&stats[f], ((red[f] + red[HID + f]) + (red[2 * HID + f] + red[3 * HID + f])));
    __syncthreads();
    red[nl * HID + f] = s2;
    __syncthreads();
    if (threadIdx.x < HID)
      atomicAdd(&stats[HID + f], ((red[f] + red[HID + f]) + (red[2 * HID + f] + red[3 * HID + f])));
  }
}

__global__ void bn_finalize_kernel(const float* __restrict__ g, const float* __restrict__ be,
                                   float* __restrict__ stats) {
  int f = threadIdx.x;
  const float inv_n = 1.f / (float)(BATCH * NPTS * K_NN);
  float m = stats[f] * inv_n;
  float v = stats[HID + f] * inv_n - m * m;
  float A = g[f] * rsqrtf(v + BN_EPS);
  stats[2 * HID + f] = A;
  stats[3 * HID + f] = be[f] - m * A;
}

// ---------------------------------------------------------------------------
__global__ __launch_bounds__(256) void pool_kernel(const float* __restrict__ h,
                                                   float* __restrict__ pooled) {
  const int b = blockIdx.x;
  const int f = threadIdx.x & 63;
  const int gsz = threadIdx.x >> 6;
  __shared__ float red[4][HID];
  float s = 0.f;
  for (int n = gsz; n < NPTS; n += 4) s += h[((size_t)b * NPTS + n) * HID + f];
  red[gsz][f] = s;
  __syncthreads();
  if (threadIdx.x < HID)
    pooled[b * HID + f] = ((red[0][f] + red[1][f]) + (red[2][f] + red[3][f])) * (1.f / (float)NPTS);
}

__global__ __launch_bounds__(256) void head_kernel(const float* __restrict__ pooled,
    const float* __restrict__ wf1, const float* __restrict__ bf1,
    const float* __restrict__ gf, const float* __restrict__ bef,
    const float* __restrict__ wf2, const float* __restrict__ bf2,
    float* __restrict__ out) {
  __shared__ float pl[BATCH * HID];
  __shared__ float t[BATCH * 32];
  __shared__ float Ab[32], Bb[32];
  for (int i = threadIdx.x; i < BATCH * HID; i += 256) pl[i] = pooled[i];
  __syncthreads();
  for (int i = threadIdx.x; i < BATCH * 32; i += 256) {
    int s = i >> 5, f1 = i & 31;
    float acc = bf1[f1];
    for (int h = 0; h < HID; ++h) acc = fmaf(pl[s * HID + h], wf1[h * 32 + f1], acc);
    t[i] = acc;
  }
  __syncthreads();
  if (threadIdx.x < 32) {
    int f1 = threadIdx.x;
    float m = 0.f;
    for (int s = 0; s < BATCH; ++s) m += t[s * 32 + f1];
    m *= (1.f / (float)BATCH);
    float v = 0.f;
    for (int s = 0; s < BATCH; ++s) { float d = t[s * 32 + f1] - m; v = fmaf(d, d, v); }
    v *= (1.f / (float)BATCH);
    float A = gf[f1] * rsqrtf(v + BN_EPS);
    Ab[f1] = A; Bb[f1] = bef[f1] - m * A;
  }
  __syncthreads();
  for (int i = threadIdx.x; i < BATCH * 32; i += 256) {
    int f1 = i & 31;
    t[i] = fmaxf(fmaf(Ab[f1], t[i], Bb[f1]), 0.f);
  }
  __syncthreads();
  if (threadIdx.x < BATCH * 2) {
    int s = threadIdx.x >> 1, o = threadIdx.x & 1;
    float acc = bf2[o];
    for (int f1 = 0; f1 < 32; ++f1) acc = fmaf(t[s * 32 + f1], wf2[f1 * 2 + o], acc);
    out[s * 2 + o] = acc;
  }
}

// ---------------------------------------------------------------------------
extern "C" void kernel_launch(void* const* d_in, const int* in_sizes, int n_in,
                              void* d_out, int out_size, void* d_ws, size_t ws_size,
                              hipStream_t stream) {
  const float* x   = (const float*)d_in[0];
  const float* w0a = (const float*)d_in[1];
  const float* b0a = (const float*)d_in[2];
  const float* g0  = (const float*)d_in[3];
  const float* be0 = (const float*)d_in[4];
  const float* w0b = (const float*)d_in[5];
  const float* b0b = (const float*)d_in[6];
  const float* wa  = (const float*)d_in[7];
  const float* ba  = (const float*)d_in[8];
  const float* ga  = (const float*)d_in[9];
  const float* bea = (const float*)d_in[10];
  const float* wb  = (const float*)d_in[11];
  const float* bb  = (const float*)d_in[12];
  const float* wf1 = (const float*)d_in[13];
  const float* bf1 = (const float*)d_in[14];
  const float* gf  = (const float*)d_in[15];
  const float* bef = (const float*)d_in[16];
  const float* wf2 = (const float*)d_in[17];
  const float* bf2 = (const float*)d_in[18];

  float* ws = (float*)d_ws;
  const size_t HN = (size_t)BATCH * NPTS * HID;         // 2,097,152
  const size_t ROWS = (size_t)BATCH * NPTS;             // 32768
  float* bufA   = ws;
  float* bufB   = bufA + HN;
  int*   idxb   = (int*)(bufB + HN);                    // ROWS*12 i
  float* d2buf  = (float*)(idxb + ROWS * K_NN);         // ROWS f
  float* stats  = d2buf + ROWS;                         // 256 f
  float* pooled = stats + 4 * HID;                      // 2048 f

  auto layer = [&](const float* cur, float* nxt, const float* W1, const float* b1p,
                   const float* g, const float* be, const float* W2, const float* b2p,
                   bool first) {
    if (first) {
      d2_kernel<3 ><<<(int)(ROWS / 256), 256, 0, stream>>>(cur, d2buf);
      knn_kernel<3 ><<<dim3(16, BATCH), 512, 0, stream>>>(cur, d2buf, idxb);
    } else {
      d2_kernel<HID><<<(int)(ROWS / 256), 256, 0, stream>>>(cur, d2buf);
      knn_kernel<HID><<<dim3(16, BATCH), 512, 0, stream>>>(cur, d2buf, idxb);
    }
    hipMemsetAsync(stats, 0, 2 * HID * sizeof(float), stream);
    if (first) edgeconv_kernel<3,   true ><<<512, 256, 0, stream>>>(cur, idxb, W1, b1p, nullptr, nullptr, stats, nullptr);
    else       edgeconv_kernel<HID, true ><<<512, 256, 0, stream>>>(cur, idxb, W1, b1p, nullptr, nullptr, stats, nullptr);
    bn_finalize_kernel<<<1, HID, 0, stream>>>(g, be, stats);
    if (first) edgeconv_kernel<3,   false><<<512, 256, 0, stream>>>(cur, idxb, W1, b1p, W2, b2p, stats, nxt);
    else       edgeconv_kernel<HID, false><<<512, 256, 0, stream>>>(cur, idxb, W1, b1p, W2, b2p, stats, nxt);
  };

  layer(x,    bufA, w0a,               b0a,      g0,       be0,       w0b,              b0b,      true);
  layer(bufA, bufB, wa + 0 * 128 * 64, ba + 0,   ga + 0,   bea + 0,   wb + 0 * 64 * 64, bb + 0,   false);
  layer(bufB, bufA, wa + 1 * 128 * 64, ba + 64,  ga + 64,  bea + 64,  wb + 1 * 64 * 64, bb + 64,  false);
  layer(bufA, bufB, wa + 2 * 128 * 64, ba + 128, ga + 128, bea + 128, wb + 2 * 64 * 64, bb + 128, false);

  pool_kernel<<<BATCH, 256, 0, stream>>>(bufB, pooled);
  head_kernel<<<1, 256, 0, stream>>>(pooled, wf1, bf1, gf, bef, wf2, bf2, (float*)d_out);
}

// Round 4
// 1991.272 us; speedup vs baseline: 1.8740x; 1.0186x over previous
//
#include <hip/hip_runtime.h>
#include <cstddef>

#define BATCH 32
#define NPTS  1024
#define K_NN  12
#define HID   64
#define BN_EPS 1e-5f

// ---------------------------------------------------------------------------
// d2[j] = ||x_j||^2 precompute.
// ---------------------------------------------------------------------------
template<int C>
__global__ __launch_bounds__(256) void d2_kernel(const float* __restrict__ x,
                                                 float* __restrict__ d2) {
  int gid = blockIdx.x * 256 + threadIdx.x;          // < B*N
  const float* xp = x + (size_t)gid * C;
  float s;
  if constexpr (C % 4 == 0) {
    const float4* x4 = (const float4*)xp;
    float a0 = 0.f, a1 = 0.f, a2 = 0.f, a3 = 0.f;
#pragma unroll
    for (int q = 0; q < C / 4; ++q) {
      float4 v = x4[q];
      a0 = fmaf(v.x, v.x, a0); a1 = fmaf(v.y, v.y, a1);
      a2 = fmaf(v.z, v.z, a2); a3 = fmaf(v.w, v.w, a3);
    }
    s = (a0 + a1) + (a2 + a3);
  } else {
    s = 0.f;
#pragma unroll
    for (int c = 0; c < C; ++c) { float v = xp[c]; s = fmaf(v, v, s); }
  }
  d2[gid] = s;
}

// ---------------------------------------------------------------------------
// kNN: lane = point i (xi register-resident), j wave-uniform via readfirstlane
// -> xj/d2j are s_loads (R3: SGPR_Count=112 confirms). __launch_bounds__(512,2)
// raises the VGPR budget to 256 so xi[64] gets REAL VGPRs (R3: budget 64 ->
// compiler parked xi in AGPRs, ~2x VALU from v_accvgpr_read per FMA).
// ---------------------------------------------------------------------------
template<int C>
__global__ __launch_bounds__(512, 2) void knn_kernel(
    const float* __restrict__ x, const float* __restrict__ d2,
    int* __restrict__ idx) {
  const int b    = blockIdx.y;
  const int lane = threadIdx.x & 63;
  const int wv_u = __builtin_amdgcn_readfirstlane(threadIdx.x >> 6);  // 0..7, SGPR
  const int i    = blockIdx.x * 64 + lane;
  const float* xb  = x  + (size_t)b * NPTS * C;
  const float* d2b = d2 + (size_t)b * NPTS;

  constexpr int NE = 8 * K_NN;                       // 96 merge entries/row
  __shared__ float lds_d[64][NE + 1];                // stride 97: odd, no conflicts
  __shared__ int   lds_j[64][NE + 1];

  float xi[C];
  if constexpr (C % 4 == 0) {
    const float4* xr = (const float4*)(xb + (size_t)i * C);
#pragma unroll
    for (int q = 0; q < C / 4; ++q) {
      float4 v = xr[q];
      xi[4 * q + 0] = v.x; xi[4 * q + 1] = v.y;
      xi[4 * q + 2] = v.z; xi[4 * q + 3] = v.w;
    }
  } else {
#pragma unroll
    for (int c = 0; c < C; ++c) xi[c] = xb[(size_t)i * C + c];
  }
  if constexpr (C >= 16) {
#pragma unroll
    for (int c = 0; c < C; ++c) asm volatile("" : "+v"(xi[c]));  // pin: no remat
  }

  float bd[K_NN]; int bj[K_NN];
#pragma unroll
  for (int k = 0; k < K_NN; ++k) { bd[k] = 3.4e38f; bj[k] = 0x7fffffff; }

  const int j0 = wv_u * (NPTS / 8);                  // uniform
#pragma unroll 1
  for (int jj = 0; jj < NPTS / 8; ++jj) {
    const int j = j0 + jj;                           // uniform
    const float* xj = xb + (size_t)j * C;            // uniform -> s_load
    const float d2j = d2b[j];                        // uniform -> s_load
    float dot;
    if constexpr (C % 4 == 0) {
      float a0 = 0.f, a1 = 0.f, a2 = 0.f, a3 = 0.f;
#pragma unroll
      for (int c = 0; c < C; c += 4) {
        a0 = fmaf(xi[c + 0], xj[c + 0], a0);
        a1 = fmaf(xi[c + 1], xj[c + 1], a1);
        a2 = fmaf(xi[c + 2], xj[c + 2], a2);
        a3 = fmaf(xi[c + 3], xj[c + 3], a3);
      }
      dot = (a0 + a1) + (a2 + a3);
    } else {
      dot = 0.f;
#pragma unroll
      for (int c = 0; c < C; ++c) dot = fmaf(xi[c], xj[c], dot);
    }
    // d2_i (row-constant) dropped: doesn't change per-row top-k order.
    const float dval = fmaf(-2.f, dot, d2j);
    if (dval < bd[K_NN - 1]) {                       // strict <: scanning j
      float dk = dval; int jk = j;                   // ascending keeps lower j
#pragma unroll
      for (int s = 0; s < K_NN; ++s) {               // branchless sorted insert
        bool sw = dk < bd[s];
        float nd = fminf(dk, bd[s]);
        float xd = fmaxf(dk, bd[s]);
        int nj = sw ? jk : bj[s];
        int xjj = sw ? bj[s] : jk;
        bd[s] = nd; bj[s] = nj; dk = xd; jk = xjj;
      }
    }
  }

#pragma unroll
  for (int k = 0; k < K_NN; ++k) {
    lds_d[lane][wv_u * K_NN + k] = bd[k];
    lds_j[lane][wv_u * K_NN + k] = bj[k];
  }
  __syncthreads();

  if (wv_u == 0) {                                   // merge 8 sorted slices
    float md[K_NN]; int mj[K_NN];
#pragma unroll
    for (int k = 0; k < K_NN; ++k) { md[k] = 3.4e38f; mj[k] = 0x7fffffff; }
    for (int e = 0; e < NE; ++e) {                   // ascending slice order ->
      float dk = lds_d[lane][e]; int jk = lds_j[lane][e];  // stability kept
      if (dk < md[K_NN - 1]) {
#pragma unroll
        for (int s = 0; s < K_NN; ++s) {
          bool sw = dk < md[s];
          float nd = fminf(dk, md[s]);
          float xd = fmaxf(dk, md[s]);
          int nj = sw ? jk : mj[s];
          int xjj = sw ? mj[s] : jk;
          md[s] = nd; mj[s] = nj; dk = xd; jk = xjj;
        }
      }
    }
    int* op = idx + ((size_t)b * NPTS + blockIdx.x * 64 + lane) * K_NN;
#pragma unroll
    for (int k = 0; k < K_NN; ++k) op[k] = mj[k];
  }
}

// ---------------------------------------------------------------------------
// wprep: W1c[i] = W1a[i] - W1b[i] for layers 1..3 (wa[i]: [128][64] row-major).
// ---------------------------------------------------------------------------
__global__ __launch_bounds__(256) void wprep_kernel(const float* __restrict__ wa,
                                                    float* __restrict__ w1c) {
  int t = blockIdx.x * 256 + threadIdx.x;            // < 3*4096
  int i = t >> 12, r = t & 4095;
  w1c[t] = wa[i * 8192 + r] - wa[i * 8192 + 4096 + r];
}

// ---------------------------------------------------------------------------
// rowgemm: Y[r][f] = bias[f] + scale * sum_c X[r][c] * W[c][f],  R x 64 @ 64x64.
// Thread: 2 rows x 4 f. W staged in LDS ([c][f] row-major, b128 per lane, 2-way
// bank alias = free). X read from global (16 lanes share an address -> 1 fetch).
// ---------------------------------------------------------------------------
__global__ __launch_bounds__(256) void rowgemm_kernel(
    const float* __restrict__ X, const float* __restrict__ W,
    const float* __restrict__ bias, float scale, float* __restrict__ Y) {
  __shared__ float w_s[HID * HID];
  for (int t = threadIdx.x; t < HID * HID; t += 256) w_s[t] = W[t];
  __syncthreads();

  const int lane = threadIdx.x & 63;
  const int wv   = threadIdx.x >> 6;
  const int fq   = lane & 15;                        // 4 f's: 4fq..4fq+3
  const int rg   = lane >> 4;                        // 4 row-groups x 2 rows
  const int r0   = blockIdx.x * 32 + wv * 8 + rg * 2;

  const float4* X4 = (const float4*)X;               // row = 16 float4
  const float4* W4 = (const float4*)w_s;
  float a0[4] = {0.f, 0.f, 0.f, 0.f}, a1[4] = {0.f, 0.f, 0.f, 0.f};

#pragma unroll 4
  for (int cq = 0; cq < 16; ++cq) {
    float4 xa = X4[(size_t)r0 * 16 + cq];
    float4 xb_ = X4[(size_t)(r0 + 1) * 16 + cq];
    float ea[4] = {xa.x, xa.y, xa.z, xa.w};
    float eb[4] = {xb_.x, xb_.y, xb_.z, xb_.w};
#pragma unroll
    for (int d = 0; d < 4; ++d) {
      float4 wv4 = W4[(cq * 4 + d) * 16 + fq];
      float w[4] = {wv4.x, wv4.y, wv4.z, wv4.w};
#pragma unroll
      for (int k = 0; k < 4; ++k) {
        a0[k] = fmaf(ea[d], w[k], a0[k]);
        a1[k] = fmaf(eb[d], w[k], a1[k]);
      }
    }
  }
  float4 b4 = ((const float4*)bias)[fq];
  float bb[4] = {b4.x, b4.y, b4.z, b4.w};
  float4 o0, o1;
  o0.x = fmaf(scale, a0[0], bb[0]); o0.y = fmaf(scale, a0[1], bb[1]);
  o0.z = fmaf(scale, a0[2], bb[2]); o0.w = fmaf(scale, a0[3], bb[3]);
  o1.x = fmaf(scale, a1[0], bb[0]); o1.y = fmaf(scale, a1[1], bb[1]);
  o1.z = fmaf(scale, a1[2], bb[2]); o1.w = fmaf(scale, a1[3], bb[3]);
  ((float4*)Y)[(size_t)r0 * 16 + fq] = o0;
  ((float4*)Y)[(size_t)(r0 + 1) * 16 + fq] = o1;
}

// ---------------------------------------------------------------------------
// edge64: per edge (n,k): h = hxi[n][f] + sum_c xj[c]*W1b[c][f].
// STATS: accumulate sum/sumsq of h into stats[0..127] (atomics).
// APPLY: hsum[n][f] = sum_k relu(A[f]*h+B[f])  (W2+mean folded into rowgemm).
// Block: 64 nodes, 16 iters x 4 nodes (1 node/wave). lane=(eg:4, fq:16):
// 3 edges x 4 f accumulators; per 4c: 3 b128 edge reads (broadcast) + 4 b128
// W reads (2-way alias, free) vs 48 FMA -> VALU-bound.
// ---------------------------------------------------------------------------
template<bool STATS>
__global__ __launch_bounds__(256) void edge64_kernel(
    const float* __restrict__ xcur, const int* __restrict__ idx,
    const float* __restrict__ w1b, const float* __restrict__ hxi,
    float* __restrict__ stats, float* __restrict__ hsum) {
  __shared__ float w_s[HID * HID];                   // 16 KB
  __shared__ float ept[4 * K_NN * 68];               // 4 nodes x 12 edges x 68
  __shared__ int   idxs[4 * K_NN];

  for (int t = threadIdx.x; t < HID * HID; t += 256) w_s[t] = w1b[t];

  const int lane = threadIdx.x & 63;
  const int wv   = threadIdx.x >> 6;                 // node-in-group
  const int fq   = lane & 15;
  const int eg   = lane >> 4;                        // 4 edge-groups x 3 edges
  const int node0 = blockIdx.x * 64;                 // global row b*N+n
  const int bbase = (node0 >> 10) << 10;             // b*N

  float A4[4], B4[4];
  if constexpr (!STATS) {
    float4 a = ((const float4*)(stats + 2 * HID))[fq];
    float4 bq = ((const float4*)(stats + 3 * HID))[fq];
    A4[0] = a.x; A4[1] = a.y; A4[2] = a.z; A4[3] = a.w;
    B4[0] = bq.x; B4[1] = bq.y; B4[2] = bq.z; B4[3] = bq.w;
  }
  float s1[4] = {0.f, 0.f, 0.f, 0.f}, s2[4] = {0.f, 0.f, 0.f, 0.f};

  const float4* W4 = (const float4*)w_s;

  for (int it = 0; it < 16; ++it) {
    const int nbase = node0 + it * 4;
    __syncthreads();                                 // prev-iter ept reads done
    if (threadIdx.x < 4 * K_NN)
      idxs[threadIdx.x] = idx[(size_t)nbase * K_NN + threadIdx.x];
    __syncthreads();
    {                                                // gather 48 edge rows
      const int q = threadIdx.x & 15;
      for (int rr = threadIdx.x >> 4; rr < 4 * K_NN; rr += 16) {
        int j = idxs[rr];
        float4 v = ((const float4*)xcur)[(size_t)(bbase + j) * 16 + q];
        *(float4*)&ept[rr * 68 + 4 * q] = v;
      }
    }
    __syncthreads();

    float acc[3][4];
#pragma unroll
    for (int e = 0; e < 3; ++e)
#pragma unroll
      for (int k = 0; k < 4; ++k) acc[e][k] = 0.f;

    const float* ep0 = ept + (wv * K_NN + 3 * eg) * 68;
#pragma unroll 4
    for (int cq = 0; cq < 16; ++cq) {
      float4 e0 = *(const float4*)(ep0 + 0 * 68 + 4 * cq);
      float4 e1 = *(const float4*)(ep0 + 1 * 68 + 4 * cq);
      float4 e2 = *(const float4*)(ep0 + 2 * 68 + 4 * cq);
      float ea[3][4] = {{e0.x, e0.y, e0.z, e0.w},
                        {e1.x, e1.y, e1.z, e1.w},
                        {e2.x, e2.y, e2.z, e2.w}};
#pragma unroll
      for (int d = 0; d < 4; ++d) {
        float4 wv4 = W4[(cq * 4 + d) * 16 + fq];
        float w[4] = {wv4.x, wv4.y, wv4.z, wv4.w};
#pragma unroll
        for (int e = 0; e < 3; ++e)
#pragma unroll
          for (int k = 0; k < 4; ++k)
            acc[e][k] = fmaf(ea[e][d], w[k], acc[e][k]);
      }
    }

    float4 hx = ((const float4*)hxi)[(size_t)(nbase + wv) * 16 + fq];
    float hxa[4] = {hx.x, hx.y, hx.z, hx.w};
    if constexpr (STATS) {
#pragma unroll
      for (int e = 0; e < 3; ++e)
#pragma unroll
        for (int k = 0; k < 4; ++k) {
          float h = acc[e][k] + hxa[k];
          s1[k] += h;
          s2[k] = fmaf(h, h, s2[k]);
        }
    } else {
      float p[4];
#pragma unroll
      for (int k = 0; k < 4; ++k) {
        float h0 = acc[0][k] + hxa[k];
        float h1 = acc[1][k] + hxa[k];
        float h2 = acc[2][k] + hxa[k];
        p[k] = fmaxf(fmaf(A4[k], h0, B4[k]), 0.f)
             + fmaxf(fmaf(A4[k], h1, B4[k]), 0.f)
             + fmaxf(fmaf(A4[k], h2, B4[k]), 0.f);
      }
#pragma unroll
      for (int k = 0; k < 4; ++k) {                  // reduce over eg (4 groups)
        p[k] += __shfl_xor(p[k], 16, 64);
        p[k] += __shfl_xor(p[k], 32, 64);
      }
      if (eg == 0) {
        float4 o; o.x = p[0]; o.y = p[1]; o.z = p[2]; o.w = p[3];
        ((float4*)hsum)[(size_t)(nbase + wv) * 16 + fq] = o;
      }
    }
  }

  if constexpr (STATS) {
#pragma unroll
    for (int k = 0; k < 4; ++k) {
      s1[k] += __shfl_xor(s1[k], 16, 64);
      s1[k] += __shfl_xor(s1[k], 32, 64);
      s2[k] += __shfl_xor(s2[k], 16, 64);
      s2[k] += __shfl_xor(s2[k], 32, 64);
    }
    if (eg == 0) {
#pragma unroll
      for (int k = 0; k < 4; ++k) {
        atomicAdd(&stats[4 * fq + k], s1[k]);
        atomicAdd(&stats[HID + 4 * fq + k], s2[k]);
      }
    }
  }
}

// ---------------------------------------------------------------------------
// Old-path EdgeConv (kept for layer 0, C=3 — cheap there).
// ---------------------------------------------------------------------------
template<int C, bool STATS>
__global__ __launch_bounds__(256) void edgeconv_kernel(
    const float* __restrict__ xcur, const int* __restrict__ idx,
    const float* __restrict__ W1, const float* __restrict__ b1,
    const float* __restrict__ W2, const float* __restrict__ b2,
    float* __restrict__ stats, float* __restrict__ out) {
  constexpr int C2 = 2 * C;
  __shared__ float w1s[C2 * HID];
  __shared__ float w2s[STATS ? 1 : HID * HID];
  __shared__ float xis[4 * C];
  __shared__ float ejs[4 * K_NN * C];
  __shared__ int   idxs[4 * K_NN];
  __shared__ float red[4 * HID];

  for (int t = threadIdx.x; t < C2 * HID; t += 256) w1s[t] = W1[t];
  if constexpr (!STATS)
    for (int t = threadIdx.x; t < HID * HID; t += 256) w2s[t] = W2[t];

  const int f  = threadIdx.x & 63;
  const int nl = threadIdx.x >> 6;
  const float b1f = b1[f];
  float A = 0.f, Bc = 0.f, b2f = 0.f;
  if constexpr (!STATS) { A = stats[2 * HID + f]; Bc = stats[3 * HID + f]; b2f = b2[f]; }
  float s1 = 0.f, s2 = 0.f;

  const int node0 = blockIdx.x * 64;
  const int nbb = (node0 >> 10) << 10;
  __syncthreads();

  for (int g4 = 0; g4 < 16; ++g4) {
    const int nbase = node0 + g4 * 4;
    __syncthreads();
    if (threadIdx.x < 4 * K_NN)
      idxs[threadIdx.x] = idx[(size_t)nbase * K_NN + threadIdx.x];
    for (int t = threadIdx.x; t < 4 * C; t += 256) {
      int n2 = t / C, c = t - n2 * C;
      xis[t] = xcur[(size_t)(nbase + n2) * C + c];
    }
    __syncthreads();
    for (int t = threadIdx.x; t < 4 * K_NN * C; t += 256) {
      int e_l = t / C, c = t - e_l * C;
      int n2 = e_l / K_NN;
      int j = idxs[e_l];
      ejs[t] = xcur[(size_t)(nbb + j) * C + c] - xis[n2 * C + c];
    }
    __syncthreads();

    float hxi = b1f;
#pragma unroll
    for (int c = 0; c < C; ++c) hxi = fmaf(xis[nl * C + c], w1s[c * HID + f], hxi);

    float hsum = 0.f;
#pragma unroll
    for (int kq = 0; kq < K_NN / 4; ++kq) {
      float h0 = hxi, h1 = hxi, h2 = hxi, h3 = hxi;
      const float* ep = ejs + (nl * K_NN + kq * 4) * C;
#pragma unroll
      for (int c = 0; c < C; ++c) {
        float w = w1s[(C + c) * HID + f];
        h0 = fmaf(ep[0 * C + c], w, h0);
        h1 = fmaf(ep[1 * C + c], w, h1);
        h2 = fmaf(ep[2 * C + c], w, h2);
        h3 = fmaf(ep[3 * C + c], w, h3);
      }
      if constexpr (STATS) {
        s1 += (h0 + h1) + (h2 + h3);
        s2 = fmaf(h0, h0, s2); s2 = fmaf(h1, h1, s2);
        s2 = fmaf(h2, h2, s2); s2 = fmaf(h3, h3, s2);
      } else {
        hsum += fmaxf(fmaf(A, h0, Bc), 0.f) + fmaxf(fmaf(A, h1, Bc), 0.f)
              + fmaxf(fmaf(A, h2, Bc), 0.f) + fmaxf(fmaf(A, h3, Bc), 0.f);
      }
    }

    if constexpr (!STATS) {
      red[nl * HID + f] = hsum;
      __syncthreads();
      float acc = 0.f;
#pragma unroll 8
      for (int h = 0; h < HID; ++h) acc = fmaf(red[nl * HID + h], w2s[h * HID + f], acc);
      out[(size_t)(nbase + nl) * HID + f] = fmaf(acc, 1.f / (float)K_NN, b2f);
    }
  }

  if constexpr (STATS) {
    red[nl * HID + f] = s1;
    __syncthreads();
    if (threadIdx.x < HID)
      atomicAdd(&stats[f], ((red[f] + red[HID + f]) + (red[2 * HID + f] + red[3 * HID + f])));
    __syncthreads();
    red[nl * HID + f] = s2;
    __syncthreads();
    if (threadIdx.x < HID)
      atomicAdd(&stats[HID + f], ((red[f] + red[HID + f]) + (red[2 * HID + f] + red[3 * HID + f])));
  }
}

__global__ void bn_finalize_kernel(const float* __restrict__ g, const float* __restrict__ be,
                                   float* __restrict__ stats) {
  int f = threadIdx.x;
  const float inv_n = 1.f / (float)(BATCH * NPTS * K_NN);
  float m = stats[f] * inv_n;
  float v = stats[HID + f] * inv_n - m * m;
  float A = g[f] * rsqrtf(v + BN_EPS);
  stats[2 * HID + f] = A;
  stats[3 * HID + f] = be[f] - m * A;
}

// ---------------------------------------------------------------------------
__global__ __launch_bounds__(256) void pool_kernel(const float* __restrict__ h,
                                                   float* __restrict__ pooled) {
  const int b = blockIdx.x;
  const int f = threadIdx.x & 63;
  const int gsz = threadIdx.x >> 6;
  __shared__ float red[4][HID];
  float s = 0.f;
  for (int n = gsz; n < NPTS; n += 4) s += h[((size_t)b * NPTS + n) * HID + f];
  red[gsz][f] = s;
  __syncthreads();
  if (threadIdx.x < HID)
    pooled[b * HID + f] = ((red[0][f] + red[1][f]) + (red[2][f] + red[3][f])) * (1.f / (float)NPTS);
}

__global__ __launch_bounds__(256) void head_kernel(const float* __restrict__ pooled,
    const float* __restrict__ wf1, const float* __restrict__ bf1,
    const float* __restrict__ gf, const float* __restrict__ bef,
    const float* __restrict__ wf2, const float* __restrict__ bf2,
    float* __restrict__ out) {
  __shared__ float pl[BATCH * HID];
  __shared__ float t[BATCH * 32];
  __shared__ float Ab[32], Bb[32];
  for (int i = threadIdx.x; i < BATCH * HID; i += 256) pl[i] = pooled[i];
  __syncthreads();
  for (int i = threadIdx.x; i < BATCH * 32; i += 256) {
    int s = i >> 5, f1 = i & 31;
    float acc = bf1[f1];
    for (int h = 0; h < HID; ++h) acc = fmaf(pl[s * HID + h], wf1[h * 32 + f1], acc);
    t[i] = acc;
  }
  __syncthreads();
  if (threadIdx.x < 32) {
    int f1 = threadIdx.x;
    float m = 0.f;
    for (int s = 0; s < BATCH; ++s) m += t[s * 32 + f1];
    m *= (1.f / (float)BATCH);
    float v = 0.f;
    for (int s = 0; s < BATCH; ++s) { float d = t[s * 32 + f1] - m; v = fmaf(d, d, v); }
    v *= (1.f / (float)BATCH);
    float A = gf[f1] * rsqrtf(v + BN_EPS);
    Ab[f1] = A; Bb[f1] = bef[f1] - m * A;
  }
  __syncthreads();
  for (int i = threadIdx.x; i < BATCH * 32; i += 256) {
    int f1 = i & 31;
    t[i] = fmaxf(fmaf(Ab[f1], t[i], Bb[f1]), 0.f);
  }
  __syncthreads();
  if (threadIdx.x < BATCH * 2) {
    int s = threadIdx.x >> 1, o = threadIdx.x & 1;
    float acc = bf2[o];
    for (int f1 = 0; f1 < 32; ++f1) acc = fmaf(t[s * 32 + f1], wf2[f1 * 2 + o], acc);
    out[s * 2 + o] = acc;
  }
}

// ---------------------------------------------------------------------------
extern "C" void kernel_launch(void* const* d_in, const int* in_sizes, int n_in,
                              void* d_out, int out_size, void* d_ws, size_t ws_size,
                              hipStream_t stream) {
  const float* x   = (const float*)d_in[0];
  const float* w0a = (const float*)d_in[1];
  const float* b0a = (const float*)d_in[2];
  const float* g0  = (const float*)d_in[3];
  const float* be0 = (const float*)d_in[4];
  const float* w0b = (const float*)d_in[5];
  const float* b0b = (const float*)d_in[6];
  const float* wa  = (const float*)d_in[7];
  const float* ba  = (const float*)d_in[8];
  const float* ga  = (const float*)d_in[9];
  const float* bea = (const float*)d_in[10];
  const float* wb  = (const float*)d_in[11];
  const float* bb  = (const float*)d_in[12];
  const float* wf1 = (const float*)d_in[13];
  const float* bf1 = (const float*)d_in[14];
  const float* gf  = (const float*)d_in[15];
  const float* bef = (const float*)d_in[16];
  const float* wf2 = (const float*)d_in[17];
  const float* bf2 = (const float*)d_in[18];

  float* ws = (float*)d_ws;
  const size_t HN = (size_t)BATCH * NPTS * HID;         // 2,097,152
  const size_t ROWS = (size_t)BATCH * NPTS;             // 32768
  float* bufA   = ws;                                   // HN
  float* bufB   = bufA + HN;                            // HN
  float* hxi    = bufB + HN;                            // HN
  float* hsm    = hxi + HN;                             // HN
  float* w1c    = hsm + HN;                             // 3*4096
  int*   idxb   = (int*)(w1c + 3 * 4096);               // ROWS*12
  float* d2buf  = (float*)(idxb + ROWS * K_NN);         // ROWS
  float* stats  = d2buf + ROWS;                         // 256
  float* pooled = stats + 4 * HID;                      // 2048
  // total ~35.5 MB of workspace

  wprep_kernel<<<48, 256, 0, stream>>>(wa, w1c);

  // ---- layer 0 (C=3, old path) ----
  d2_kernel<3><<<(int)(ROWS / 256), 256, 0, stream>>>(x, d2buf);
  knn_kernel<3><<<dim3(16, BATCH), 512, 0, stream>>>(x, d2buf, idxb);
  hipMemsetAsync(stats, 0, 2 * HID * sizeof(float), stream);
  edgeconv_kernel<3, true ><<<512, 256, 0, stream>>>(x, idxb, w0a, b0a, nullptr, nullptr, stats, nullptr);
  bn_finalize_kernel<<<1, HID, 0, stream>>>(g0, be0, stats);
  edgeconv_kernel<3, false><<<512, 256, 0, stream>>>(x, idxb, w0a, b0a, w0b, b0b, stats, bufA);

  // ---- layers 1..3 (new path) ----
  const float* cur = bufA;
  float* nxt = bufB;
  for (int i = 0; i < 3; ++i) {
    const float* W1b = wa + (size_t)i * 8192 + 4096;
    d2_kernel<HID><<<(int)(ROWS / 256), 256, 0, stream>>>(cur, d2buf);
    knn_kernel<HID><<<dim3(16, BATCH), 512, 0, stream>>>(cur, d2buf, idxb);
    rowgemm_kernel<<<(int)(ROWS / 32), 256, 0, stream>>>(cur, w1c + (size_t)i * 4096,
                                                         ba + i * HID, 1.0f, hxi);
    hipMemsetAsync(stats, 0, 2 * HID * sizeof(float), stream);
    edge64_kernel<true ><<<512, 256, 0, stream>>>(cur, idxb, W1b, hxi, stats, nullptr);
    bn_finalize_kernel<<<1, HID, 0, stream>>>(ga + i * HID, bea + i * HID, stats);
    edge64_kernel<false><<<512, 256, 0, stream>>>(cur, idxb, W1b, hxi, stats, hsm);
    rowgemm_kernel<<<(int)(ROWS / 32), 256, 0, stream>>>(hsm, wb + (size_t)i * 4096,
                                                         bb + i * HID, 1.f / (float)K_NN, nxt);
    const float* t = cur; cur = nxt; nxt = (float*)t;
  }

  pool_kernel<<<BATCH, 256, 0, stream>>>(cur, pooled);
  head_kernel<<<1, 256, 0, stream>>>(pooled, wf1, bf1, gf, bef, wf2, bf2, (float*)d_out);
}

// Round 5
// 1144.368 us; speedup vs baseline: 3.2608x; 1.7401x over previous
//
#include <hip/hip_runtime.h>
#include <cstddef>

#define BATCH 32
#define NPTS  1024
#define K_NN  12
#define HID   64
#define BN_EPS 1e-5f

// ---------------------------------------------------------------------------
// d2[j] = ||x_j||^2 precompute.
// ---------------------------------------------------------------------------
template<int C>
__global__ __launch_bounds__(256) void d2_kernel(const float* __restrict__ x,
                                                 float* __restrict__ d2) {
  int gid = blockIdx.x * 256 + threadIdx.x;          // < B*N
  const float* xp = x + (size_t)gid * C;
  float s;
  if constexpr (C % 4 == 0) {
    const float4* x4 = (const float4*)xp;
    float a0 = 0.f, a1 = 0.f, a2 = 0.f, a3 = 0.f;
#pragma unroll
    for (int q = 0; q < C / 4; ++q) {
      float4 v = x4[q];
      a0 = fmaf(v.x, v.x, a0); a1 = fmaf(v.y, v.y, a1);
      a2 = fmaf(v.z, v.z, a2); a3 = fmaf(v.w, v.w, a3);
    }
    s = (a0 + a1) + (a2 + a3);
  } else {
    s = 0.f;
#pragma unroll
    for (int c = 0; c < C; ++c) { float v = xp[c]; s = fmaf(v, v, s); }
  }
  d2[gid] = s;
}

// ---------------------------------------------------------------------------
// kNN: lane = point i (xi register-resident), j wave-uniform via readfirstlane
// -> xj/d2j are s_loads. __launch_bounds__(512,2) gives the 256-VGPR budget
// so xi[64] lives in real VGPRs (not AGPRs).
// ---------------------------------------------------------------------------
template<int C>
__global__ __launch_bounds__(512, 2) void knn_kernel(
    const float* __restrict__ x, const float* __restrict__ d2,
    int* __restrict__ idx) {
  const int b    = blockIdx.y;
  const int lane = threadIdx.x & 63;
  const int wv_u = __builtin_amdgcn_readfirstlane(threadIdx.x >> 6);  // 0..7, SGPR
  const int i    = blockIdx.x * 64 + lane;
  const float* xb  = x  + (size_t)b * NPTS * C;
  const float* d2b = d2 + (size_t)b * NPTS;

  constexpr int NE = 8 * K_NN;                       // 96 merge entries/row
  __shared__ float lds_d[64][NE + 1];                // stride 97: odd, no conflicts
  __shared__ int   lds_j[64][NE + 1];

  float xi[C];
  if constexpr (C % 4 == 0) {
    const float4* xr = (const float4*)(xb + (size_t)i * C);
#pragma unroll
    for (int q = 0; q < C / 4; ++q) {
      float4 v = xr[q];
      xi[4 * q + 0] = v.x; xi[4 * q + 1] = v.y;
      xi[4 * q + 2] = v.z; xi[4 * q + 3] = v.w;
    }
  } else {
#pragma unroll
    for (int c = 0; c < C; ++c) xi[c] = xb[(size_t)i * C + c];
  }
  if constexpr (C >= 16) {
#pragma unroll
    for (int c = 0; c < C; ++c) asm volatile("" : "+v"(xi[c]));  // pin: no remat
  }

  float bd[K_NN]; int bj[K_NN];
#pragma unroll
  for (int k = 0; k < K_NN; ++k) { bd[k] = 3.4e38f; bj[k] = 0x7fffffff; }

  const int j0 = wv_u * (NPTS / 8);                  // uniform
#pragma unroll 1
  for (int jj = 0; jj < NPTS / 8; ++jj) {
    const int j = j0 + jj;                           // uniform
    const float* xj = xb + (size_t)j * C;            // uniform -> s_load
    const float d2j = d2b[j];                        // uniform -> s_load
    float dot;
    if constexpr (C % 4 == 0) {
      float a0 = 0.f, a1 = 0.f, a2 = 0.f, a3 = 0.f;
#pragma unroll
      for (int c = 0; c < C; c += 4) {
        a0 = fmaf(xi[c + 0], xj[c + 0], a0);
        a1 = fmaf(xi[c + 1], xj[c + 1], a1);
        a2 = fmaf(xi[c + 2], xj[c + 2], a2);
        a3 = fmaf(xi[c + 3], xj[c + 3], a3);
      }
      dot = (a0 + a1) + (a2 + a3);
    } else {
      dot = 0.f;
#pragma unroll
      for (int c = 0; c < C; ++c) dot = fmaf(xi[c], xj[c], dot);
    }
    // d2_i (row-constant) dropped: doesn't change per-row top-k order.
    const float dval = fmaf(-2.f, dot, d2j);
    if (dval < bd[K_NN - 1]) {                       // strict <: scanning j
      float dk = dval; int jk = j;                   // ascending keeps lower j
#pragma unroll
      for (int s = 0; s < K_NN; ++s) {               // branchless sorted insert
        bool sw = dk < bd[s];
        float nd = fminf(dk, bd[s]);
        float xd = fmaxf(dk, bd[s]);
        int nj = sw ? jk : bj[s];
        int xjj = sw ? bj[s] : jk;
        bd[s] = nd; bj[s] = nj; dk = xd; jk = xjj;
      }
    }
  }

#pragma unroll
  for (int k = 0; k < K_NN; ++k) {
    lds_d[lane][wv_u * K_NN + k] = bd[k];
    lds_j[lane][wv_u * K_NN + k] = bj[k];
  }
  __syncthreads();

  if (wv_u == 0) {                                   // merge 8 sorted slices
    float md[K_NN]; int mj[K_NN];
#pragma unroll
    for (int k = 0; k < K_NN; ++k) { md[k] = 3.4e38f; mj[k] = 0x7fffffff; }
    for (int e = 0; e < NE; ++e) {                   // ascending slice order ->
      float dk = lds_d[lane][e]; int jk = lds_j[lane][e];  // stability kept
      if (dk < md[K_NN - 1]) {
#pragma unroll
        for (int s = 0; s < K_NN; ++s) {
          bool sw = dk < md[s];
          float nd = fminf(dk, md[s]);
          float xd = fmaxf(dk, md[s]);
          int nj = sw ? jk : mj[s];
          int xjj = sw ? mj[s] : jk;
          md[s] = nd; mj[s] = nj; dk = xd; jk = xjj;
        }
      }
    }
    int* op = idx + ((size_t)b * NPTS + blockIdx.x * 64 + lane) * K_NN;
#pragma unroll
    for (int k = 0; k < K_NN; ++k) op[k] = mj[k];
  }
}

// ---------------------------------------------------------------------------
// wprep: W1c[i] = W1a[i] - W1b[i] for layers 1..3 (wa[i]: [128][64] row-major).
// ---------------------------------------------------------------------------
__global__ __launch_bounds__(256) void wprep_kernel(const float* __restrict__ wa,
                                                    float* __restrict__ w1c) {
  int t = blockIdx.x * 256 + threadIdx.x;            // < 3*4096
  int i = t >> 12, r = t & 4095;
  w1c[t] = wa[i * 8192 + r] - wa[i * 8192 + 4096 + r];
}

// ---------------------------------------------------------------------------
// rowgemm: Y[r][f] = bias[f] + scale * sum_c X[r][c] * W[c][f],  R x 64 @ 64x64.
// ---------------------------------------------------------------------------
__global__ __launch_bounds__(256) void rowgemm_kernel(
    const float* __restrict__ X, const float* __restrict__ W,
    const float* __restrict__ bias, float scale, float* __restrict__ Y) {
  __shared__ float w_s[HID * HID];
  for (int t = threadIdx.x; t < HID * HID; t += 256) w_s[t] = W[t];
  __syncthreads();

  const int lane = threadIdx.x & 63;
  const int wv   = threadIdx.x >> 6;
  const int fq   = lane & 15;                        // 4 f's: 4fq..4fq+3
  const int rg   = lane >> 4;                        // 4 row-groups x 2 rows
  const int r0   = blockIdx.x * 32 + wv * 8 + rg * 2;

  const float4* X4 = (const float4*)X;               // row = 16 float4
  const float4* W4 = (const float4*)w_s;
  float a0[4] = {0.f, 0.f, 0.f, 0.f}, a1[4] = {0.f, 0.f, 0.f, 0.f};

#pragma unroll 4
  for (int cq = 0; cq < 16; ++cq) {
    float4 xa = X4[(size_t)r0 * 16 + cq];
    float4 xb_ = X4[(size_t)(r0 + 1) * 16 + cq];
    float ea[4] = {xa.x, xa.y, xa.z, xa.w};
    float eb[4] = {xb_.x, xb_.y, xb_.z, xb_.w};
#pragma unroll
    for (int d = 0; d < 4; ++d) {
      float4 wv4 = W4[(cq * 4 + d) * 16 + fq];
      float w[4] = {wv4.x, wv4.y, wv4.z, wv4.w};
#pragma unroll
      for (int k = 0; k < 4; ++k) {
        a0[k] = fmaf(ea[d], w[k], a0[k]);
        a1[k] = fmaf(eb[d], w[k], a1[k]);
      }
    }
  }
  float bb[4] = {0.f, 0.f, 0.f, 0.f};
  if (bias) { float4 b4 = ((const float4*)bias)[fq]; bb[0]=b4.x; bb[1]=b4.y; bb[2]=b4.z; bb[3]=b4.w; }
  float4 o0, o1;
  o0.x = fmaf(scale, a0[0], bb[0]); o0.y = fmaf(scale, a0[1], bb[1]);
  o0.z = fmaf(scale, a0[2], bb[2]); o0.w = fmaf(scale, a0[3], bb[3]);
  o1.x = fmaf(scale, a1[0], bb[0]); o1.y = fmaf(scale, a1[1], bb[1]);
  o1.z = fmaf(scale, a1[2], bb[2]); o1.w = fmaf(scale, a1[3], bb[3]);
  ((float4*)Y)[(size_t)r0 * 16 + fq] = o0;
  ((float4*)Y)[(size_t)(r0 + 1) * 16 + fq] = o1;
}

// ---------------------------------------------------------------------------
// edgegather: per-edge work after the algebraic split h = hxi[n] + hxj[j].
// STATS: s1/s2 per feature -> deterministic block partials [block][128].
// APPLY: hsum[n][f] = sum_k relu(A*h+B). lane=feature, wave=node (uniform),
// 12 gathers issued as one batch (ILP latency hiding); idx row is s_load.
// ---------------------------------------------------------------------------
template<bool STATS>
__global__ __launch_bounds__(256) void edgegather_kernel(
    const int* __restrict__ idx, const float* __restrict__ hxi,
    const float* __restrict__ hxj, const float* __restrict__ stats,
    float* __restrict__ partial, float* __restrict__ hsum) {
  const int lane = threadIdx.x & 63;
  const int wv   = __builtin_amdgcn_readfirstlane(threadIdx.x >> 6);  // uniform
  const int node0 = blockIdx.x * 64;
  float A = 0.f, Bc = 0.f;
  if constexpr (!STATS) { A = stats[128 + lane]; Bc = stats[192 + lane]; }
  float s1 = 0.f, s2 = 0.f;

#pragma unroll 1
  for (int it = 0; it < 16; ++it) {
    const int n = node0 + it * 4 + wv;               // uniform
    const int bbase = (n >> 10) << 10;               // b*N
    const int* ip = idx + (size_t)n * K_NN;          // uniform -> s_load
    int j[K_NN];
#pragma unroll
    for (int k = 0; k < K_NN; ++k) j[k] = ip[k];
    const float hv = hxi[(size_t)n * HID + lane];
    float v[K_NN];
#pragma unroll
    for (int k = 0; k < K_NN; ++k)                   // 12 independent gathers
      v[k] = hxj[(size_t)(bbase + j[k]) * HID + lane];
    if constexpr (STATS) {
#pragma unroll
      for (int k = 0; k < K_NN; ++k) { float h = hv + v[k]; s1 += h; s2 = fmaf(h, h, s2); }
    } else {
      float acc = 0.f;
#pragma unroll
      for (int k = 0; k < K_NN; ++k) { float h = hv + v[k]; acc += fmaxf(fmaf(A, h, Bc), 0.f); }
      hsum[(size_t)n * HID + lane] = acc;
    }
  }

  if constexpr (STATS) {
    __shared__ float red[4][HID];
    red[wv][lane] = s1;
    __syncthreads();
    if (threadIdx.x < HID)
      partial[(size_t)blockIdx.x * 128 + lane] =
          (red[0][lane] + red[1][lane]) + (red[2][lane] + red[3][lane]);
    __syncthreads();
    red[wv][lane] = s2;
    __syncthreads();
    if (threadIdx.x < HID)
      partial[(size_t)blockIdx.x * 128 + 64 + lane] =
          (red[0][lane] + red[1][lane]) + (red[2][lane] + red[3][lane]);
  }
}

// ---------------------------------------------------------------------------
// Reduce 512 block-partials and finalize BN scale/shift into stats[128..255].
// ---------------------------------------------------------------------------
__global__ void bn_reduce_finalize_kernel(const float* __restrict__ g,
                                          const float* __restrict__ be,
                                          const float* __restrict__ partial,
                                          float* __restrict__ stats) {
  int t = threadIdx.x;                               // 0..127
  float a0 = 0.f, a1 = 0.f, a2 = 0.f, a3 = 0.f;
  for (int gb = 0; gb < 512; gb += 4) {
    a0 += partial[(size_t)(gb + 0) * 128 + t];
    a1 += partial[(size_t)(gb + 1) * 128 + t];
    a2 += partial[(size_t)(gb + 2) * 128 + t];
    a3 += partial[(size_t)(gb + 3) * 128 + t];
  }
  __shared__ float sm[128];
  sm[t] = (a0 + a1) + (a2 + a3);
  __syncthreads();
  if (t < HID) {
    const float inv_n = 1.f / (float)(BATCH * NPTS * K_NN);
    float m = sm[t] * inv_n;
    float v = sm[HID + t] * inv_n - m * m;
    float A = g[t] * rsqrtf(v + BN_EPS);
    stats[128 + t] = A;
    stats[192 + t] = be[t] - m * A;
  }
}

// ---------------------------------------------------------------------------
// Old-path EdgeConv (layer 0 only, C=3 — cheap there).
// ---------------------------------------------------------------------------
template<int C, bool STATS>
__global__ __launch_bounds__(256) void edgeconv_kernel(
    const float* __restrict__ xcur, const int* __restrict__ idx,
    const float* __restrict__ W1, const float* __restrict__ b1,
    const float* __restrict__ W2, const float* __restrict__ b2,
    float* __restrict__ stats, float* __restrict__ out) {
  constexpr int C2 = 2 * C;
  __shared__ float w1s[C2 * HID];
  __shared__ float w2s[STATS ? 1 : HID * HID];
  __shared__ float xis[4 * C];
  __shared__ float ejs[4 * K_NN * C];
  __shared__ int   idxs[4 * K_NN];
  __shared__ float red[4 * HID];

  for (int t = threadIdx.x; t < C2 * HID; t += 256) w1s[t] = W1[t];
  if constexpr (!STATS)
    for (int t = threadIdx.x; t < HID * HID; t += 256) w2s[t] = W2[t];

  const int f  = threadIdx.x & 63;
  const int nl = threadIdx.x >> 6;
  const float b1f = b1[f];
  float A = 0.f, Bc = 0.f, b2f = 0.f;
  if constexpr (!STATS) { A = stats[2 * HID + f]; Bc = stats[3 * HID + f]; b2f = b2[f]; }
  float s1 = 0.f, s2 = 0.f;

  const int node0 = blockIdx.x * 64;
  const int nbb = (node0 >> 10) << 10;
  __syncthreads();

  for (int g4 = 0; g4 < 16; ++g4) {
    const int nbase = node0 + g4 * 4;
    __syncthreads();
    if (threadIdx.x < 4 * K_NN)
      idxs[threadIdx.x] = idx[(size_t)nbase * K_NN + threadIdx.x];
    for (int t = threadIdx.x; t < 4 * C; t += 256) {
      int n2 = t / C, c = t - n2 * C;
      xis[t] = xcur[(size_t)(nbase + n2) * C + c];
    }
    __syncthreads();
    for (int t = threadIdx.x; t < 4 * K_NN * C; t += 256) {
      int e_l = t / C, c = t - e_l * C;
      int n2 = e_l / K_NN;
      int j = idxs[e_l];
      ejs[t] = xcur[(size_t)(nbb + j) * C + c] - xis[n2 * C + c];
    }
    __syncthreads();

    float hxi = b1f;
#pragma unroll
    for (int c = 0; c < C; ++c) hxi = fmaf(xis[nl * C + c], w1s[c * HID + f], hxi);

    float hsum = 0.f;
#pragma unroll
    for (int kq = 0; kq < K_NN / 4; ++kq) {
      float h0 = hxi, h1 = hxi, h2 = hxi, h3 = hxi;
      const float* ep = ejs + (nl * K_NN + kq * 4) * C;
#pragma unroll
      for (int c = 0; c < C; ++c) {
        float w = w1s[(C + c) * HID + f];
        h0 = fmaf(ep[0 * C + c], w, h0);
        h1 = fmaf(ep[1 * C + c], w, h1);
        h2 = fmaf(ep[2 * C + c], w, h2);
        h3 = fmaf(ep[3 * C + c], w, h3);
      }
      if constexpr (STATS) {
        s1 += (h0 + h1) + (h2 + h3);
        s2 = fmaf(h0, h0, s2); s2 = fmaf(h1, h1, s2);
        s2 = fmaf(h2, h2, s2); s2 = fmaf(h3, h3, s2);
      } else {
        hsum += fmaxf(fmaf(A, h0, Bc), 0.f) + fmaxf(fmaf(A, h1, Bc), 0.f)
              + fmaxf(fmaf(A, h2, Bc), 0.f) + fmaxf(fmaf(A, h3, Bc), 0.f);
      }
    }

    if constexpr (!STATS) {
      red[nl * HID + f] = hsum;
      __syncthreads();
      float acc = 0.f;
#pragma unroll 8
      for (int h = 0; h < HID; ++h) acc = fmaf(red[nl * HID + h], w2s[h * HID + f], acc);
      out[(size_t)(nbase + nl) * HID + f] = fmaf(acc, 1.f / (float)K_NN, b2f);
    }
  }

  if constexpr (STATS) {
    red[nl * HID + f] = s1;
    __syncthreads();
    if (threadIdx.x < HID)
      atomicAdd(&stats[f], ((red[f] + red[HID + f]) + (red[2 * HID + f] + red[3 * HID + f])));
    __syncthreads();
    red[nl * HID + f] = s2;
    __syncthreads();
    if (threadIdx.x < HID)
      atomicAdd(&stats[HID + f], ((red[f] + red[HID + f]) + (red[2 * HID + f] + red[3 * HID + f])));
  }
}

__global__ void bn_finalize_kernel(const float* __restrict__ g, const float* __restrict__ be,
                                   float* __restrict__ stats) {
  int f = threadIdx.x;
  const float inv_n = 1.f / (float)(BATCH * NPTS * K_NN);
  float m = stats[f] * inv_n;
  float v = stats[HID + f] * inv_n - m * m;
  float A = g[f] * rsqrtf(v + BN_EPS);
  stats[2 * HID + f] = A;
  stats[3 * HID + f] = be[f] - m * A;
}

// ---------------------------------------------------------------------------
__global__ __launch_bounds__(256) void pool_kernel(const float* __restrict__ h,
                                                   float* __restrict__ pooled) {
  const int b = blockIdx.x;
  const int f = threadIdx.x & 63;
  const int gsz = threadIdx.x >> 6;
  __shared__ float red[4][HID];
  float s = 0.f;
  for (int n = gsz; n < NPTS; n += 4) s += h[((size_t)b * NPTS + n) * HID + f];
  red[gsz][f] = s;
  __syncthreads();
  if (threadIdx.x < HID)
    pooled[b * HID + f] = ((red[0][f] + red[1][f]) + (red[2][f] + red[3][f])) * (1.f / (float)NPTS);
}

__global__ __launch_bounds__(256) void head_kernel(const float* __restrict__ pooled,
    const float* __restrict__ wf1, const float* __restrict__ bf1,
    const float* __restrict__ gf, const float* __restrict__ bef,
    const float* __restrict__ wf2, const float* __restrict__ bf2,
    float* __restrict__ out) {
  __shared__ float pl[BATCH * HID];
  __shared__ float t[BATCH * 32];
  __shared__ float Ab[32], Bb[32];
  for (int i = threadIdx.x; i < BATCH * HID; i += 256) pl[i] = pooled[i];
  __syncthreads();
  for (int i = threadIdx.x; i < BATCH * 32; i += 256) {
    int s = i >> 5, f1 = i & 31;
    float acc = bf1[f1];
    for (int h = 0; h < HID; ++h) acc = fmaf(pl[s * HID + h], wf1[h * 32 + f1], acc);
    t[i] = acc;
  }
  __syncthreads();
  if (threadIdx.x < 32) {
    int f1 = threadIdx.x;
    float m = 0.f;
    for (int s = 0; s < BATCH; ++s) m += t[s * 32 + f1];
    m *= (1.f / (float)BATCH);
    float v = 0.f;
    for (int s = 0; s < BATCH; ++s) { float d = t[s * 32 + f1] - m; v = fmaf(d, d, v); }
    v *= (1.f / (float)BATCH);
    float A = gf[f1] * rsqrtf(v + BN_EPS);
    Ab[f1] = A; Bb[f1] = bef[f1] - m * A;
  }
  __syncthreads();
  for (int i = threadIdx.x; i < BATCH * 32; i += 256) {
    int f1 = i & 31;
    t[i] = fmaxf(fmaf(Ab[f1], t[i], Bb[f1]), 0.f);
  }
  __syncthreads();
  if (threadIdx.x < BATCH * 2) {
    int s = threadIdx.x >> 1, o = threadIdx.x & 1;
    float acc = bf2[o];
    for (int f1 = 0; f1 < 32; ++f1) acc = fmaf(t[s * 32 + f1], wf2[f1 * 2 + o], acc);
    out[s * 2 + o] = acc;
  }
}

// ---------------------------------------------------------------------------
extern "C" void kernel_launch(void* const* d_in, const int* in_sizes, int n_in,
                              void* d_out, int out_size, void* d_ws, size_t ws_size,
                              hipStream_t stream) {
  const float* x   = (const float*)d_in[0];
  const float* w0a = (const float*)d_in[1];
  const float* b0a = (const float*)d_in[2];
  const float* g0  = (const float*)d_in[3];
  const float* be0 = (const float*)d_in[4];
  const float* w0b = (const float*)d_in[5];
  const float* b0b = (const float*)d_in[6];
  const float* wa  = (const float*)d_in[7];
  const float* ba  = (const float*)d_in[8];
  const float* ga  = (const float*)d_in[9];
  const float* bea = (const float*)d_in[10];
  const float* wb  = (const float*)d_in[11];
  const float* bb  = (const float*)d_in[12];
  const float* wf1 = (const float*)d_in[13];
  const float* bf1 = (const float*)d_in[14];
  const float* gf  = (const float*)d_in[15];
  const float* bef = (const float*)d_in[16];
  const float* wf2 = (const float*)d_in[17];
  const float* bf2 = (const float*)d_in[18];

  float* ws = (float*)d_ws;
  const size_t HN = (size_t)BATCH * NPTS * HID;         // 2,097,152
  const size_t ROWS = (size_t)BATCH * NPTS;             // 32768
  float* bufA    = ws;                                  // HN
  float* bufB    = bufA + HN;                           // HN
  float* hxi     = bufB + HN;                           // HN
  float* hxjb    = hxi + HN;                            // HN
  float* hsm     = hxjb + HN;                           // HN
  float* w1c     = hsm + HN;                            // 3*4096
  int*   idxb    = (int*)(w1c + 3 * 4096);              // ROWS*12
  float* d2buf   = (float*)(idxb + ROWS * K_NN);        // ROWS
  float* stats   = d2buf + ROWS;                        // 256
  float* partial = stats + 256;                         // 512*128
  float* pooled  = partial + 512 * 128;                 // 2048
  // total ~44 MB of workspace

  wprep_kernel<<<48, 256, 0, stream>>>(wa, w1c);

  // ---- layer 0 (C=3, old path) ----
  d2_kernel<3><<<(int)(ROWS / 256), 256, 0, stream>>>(x, d2buf);
  knn_kernel<3><<<dim3(16, BATCH), 512, 0, stream>>>(x, d2buf, idxb);
  hipMemsetAsync(stats, 0, 2 * HID * sizeof(float), stream);
  edgeconv_kernel<3, true ><<<512, 256, 0, stream>>>(x, idxb, w0a, b0a, nullptr, nullptr, stats, nullptr);
  bn_finalize_kernel<<<1, HID, 0, stream>>>(g0, be0, stats);
  edgeconv_kernel<3, false><<<512, 256, 0, stream>>>(x, idxb, w0a, b0a, w0b, b0b, stats, bufA);

  // ---- layers 1..3 (gather path) ----
  const float* cur = bufA;
  float* nxt = bufB;
  for (int i = 0; i < 3; ++i) {
    const float* W1b = wa + (size_t)i * 8192 + 4096;
    d2_kernel<HID><<<(int)(ROWS / 256), 256, 0, stream>>>(cur, d2buf);
    knn_kernel<HID><<<dim3(16, BATCH), 512, 0, stream>>>(cur, d2buf, idxb);
    rowgemm_kernel<<<(int)(ROWS / 32), 256, 0, stream>>>(cur, w1c + (size_t)i * 4096,
                                                         ba + i * HID, 1.0f, hxi);
    rowgemm_kernel<<<(int)(ROWS / 32), 256, 0, stream>>>(cur, W1b, nullptr, 1.0f, hxjb);
    edgegather_kernel<true ><<<512, 256, 0, stream>>>(idxb, hxi, hxjb, nullptr, partial, nullptr);
    bn_reduce_finalize_kernel<<<1, 128, 0, stream>>>(ga + i * HID, bea + i * HID, partial, stats);
    edgegather_kernel<false><<<512, 256, 0, stream>>>(idxb, hxi, hxjb, stats, nullptr, hsm);
    rowgemm_kernel<<<(int)(ROWS / 32), 256, 0, stream>>>(hsm, wb + (size_t)i * 4096,
                                                         bb + i * HID, 1.f / (float)K_NN, nxt);
    const float* t = cur; cur = nxt; nxt = (float*)t;
  }

  pool_kernel<<<BATCH, 256, 0, stream>>>(cur, pooled);
  head_kernel<<<1, 256, 0, stream>>>(pooled, wf1, bf1, gf, bef, wf2, bf2, (float*)d_out);
}